// Round 6
// baseline (2302.745 us; speedup 1.0000x reference)
//
#include <hip/hip_runtime.h>
#include <math.h>

typedef _Float16 half8 __attribute__((ext_vector_type(8)));
typedef float f32x16 __attribute__((ext_vector_type(16)));

// ---------------------------------------------------------------------------
// w2prep: pack w2 [64,32,3,3] into MFMA-fragment order, split hi/lo f16.
// w2p layout: hi plane [tap 9][blk 8][n 32][e 8] (18432), then lo plane.
//   blk = nt*4 + s*2 + g ; och = nt*32+n ; ic = s*16+g*8+e
// ---------------------------------------------------------------------------
__global__ __launch_bounds__(256) void w2prep_k(const float* __restrict__ w2,
                                                _Float16* __restrict__ w2p) {
  const int i = blockIdx.x * 256 + threadIdx.x;
  if (i >= 18432) return;
  const int tap = i >> 11;
  const int r = i & 2047;
  const int blk = r >> 8;
  const int nt = blk >> 2, s = (blk >> 1) & 1, g = blk & 1;
  const int n = (r >> 3) & 31, e = r & 7;
  const int och = nt * 32 + n;
  const int ic = s * 16 + g * 8 + e;
  const float v = w2[och * 288 + ic * 9 + tap];
  const _Float16 h = (_Float16)v;
  const _Float16 l = (_Float16)((v - (float)h) * 1024.0f);
  w2p[i] = h;
  w2p[18432 + i] = l;
}

// ---------------------------------------------------------------------------
// conv1: x [C,1,64,64] -> y1h/y1l [C][900 pos][32 ic^swz] f16 (split, NHWC,
// pre-swizzled: ch-block gb stored at slot gb ^ ((col>>1)&3)).
// ---------------------------------------------------------------------------
__global__ __launch_bounds__(256) void conv1_k(
    const float* __restrict__ x, const float* __restrict__ w1,
    const float* __restrict__ b1, _Float16* __restrict__ y1h,
    _Float16* __restrict__ y1l) {
  __shared__ float sIn[4096];
  __shared__ float sW[32 * 28];
  __shared__ float sB[32];
  const int img = blockIdx.x;
  const int tid = threadIdx.x;
  {
    const float4* src = (const float4*)(x + (size_t)img * 4096);
    float4* dst = (float4*)sIn;
#pragma unroll
    for (int i = 0; i < 4; ++i) dst[tid + i * 256] = src[tid + i * 256];
  }
  for (int i = tid; i < 800; i += 256) {
    int ch = i / 25, k = i % 25;
    sW[ch * 28 + k] = w1[i];
  }
  if (tid < 32) sB[tid] = b1[tid];
  __syncthreads();
  _Float16* oh = y1h + (size_t)img * 28800;
  _Float16* ol = y1l + (size_t)img * 28800;
#pragma unroll 1
  for (int it = 0; it < 2; ++it) {
    const int p0 = tid + it * 512;
    const int p1 = p0 + 256;
    const bool v1 = (p1 < 900);
    const int q1 = v1 ? p1 : 0;
    const int oy0 = p0 / 30, ox0 = p0 % 30;
    const int oy1 = q1 / 30, ox1 = q1 % 30;
    float a0[25], a1[25];
#pragma unroll
    for (int ky = 0; ky < 5; ++ky)
#pragma unroll
      for (int kx = 0; kx < 5; ++kx) {
        a0[ky * 5 + kx] = sIn[(2 * oy0 + ky) * 64 + 2 * ox0 + kx];
        a1[ky * 5 + kx] = sIn[(2 * oy1 + ky) * 64 + 2 * ox1 + kx];
      }
    float acc0[32], acc1[32];
#pragma unroll
    for (int ch = 0; ch < 32; ++ch) {
      float s0 = 0.f, s1 = 0.f;
#pragma unroll
      for (int k = 0; k < 25; ++k) {
        const float w = sW[ch * 28 + k];
        s0 += w * a0[k];
        s1 += w * a1[k];
      }
      acc0[ch] = fmaxf(s0 + sB[ch], 0.f);
      acc1[ch] = fmaxf(s1 + sB[ch], 0.f);
    }
    const int swz0 = (ox0 >> 1) & 3;
    const int swz1 = (ox1 >> 1) & 3;
#pragma unroll
    for (int gb = 0; gb < 4; ++gb) {
      half8 h0, l0;
#pragma unroll
      for (int e = 0; e < 8; ++e) {
        const float v = acc0[gb * 8 + e];
        const _Float16 hh = (_Float16)v;
        h0[e] = hh;
        l0[e] = (_Float16)((v - (float)hh) * 1024.0f);
      }
      *(float4*)&oh[p0 * 32 + (gb ^ swz0) * 8] = *(float4*)&h0;
      *(float4*)&ol[p0 * 32 + (gb ^ swz0) * 8] = *(float4*)&l0;
    }
    if (v1) {
#pragma unroll
      for (int gb = 0; gb < 4; ++gb) {
        half8 h1, l1;
#pragma unroll
        for (int e = 0; e < 8; ++e) {
          const float v = acc1[gb * 8 + e];
          const _Float16 hh = (_Float16)v;
          h1[e] = hh;
          l1[e] = (_Float16)((v - (float)hh) * 1024.0f);
        }
        *(float4*)&oh[p1 * 32 + (gb ^ swz1) * 8] = *(float4*)&h1;
        *(float4*)&ol[p1 * 32 + (gb ^ swz1) * 8] = *(float4*)&l1;
      }
    }
  }
}

// ---------------------------------------------------------------------------
// conv2 + maxpool, MFMA split-f16 implicit GEMM, v2 (pool-read FIXED).
// LDS (halfwords): Xh[0,11520) [img2][180 pos][32]; Xl[11520,23040);
//                  Wh[23040,27136) [tl2][blk8][n32][e8]; Wl[27136,31232).
// Pool overlay: float [224 pos][65] (58240 B).
// ---------------------------------------------------------------------------
__global__ __launch_bounds__(448) void conv2_mfma_k(
    const _Float16* __restrict__ y1h, const _Float16* __restrict__ y1l,
    const _Float16* __restrict__ w2p, const float* __restrict__ b2,
    float* __restrict__ y2p) {
  __shared__ __align__(16) _Float16 S[31232];
  const int rp = blockIdx.x;
  const int img0 = blockIdx.y * 2;
  const int tid = threadIdx.x;
  const int row0 = rp * 4;

  // ---- stage X: 4 linear copies (img0/img1 x hi/lo), 720 x 16B each ----
  {
    const _Float16* srcs[4];
    srcs[0] = y1h + (size_t)img0 * 28800 + row0 * 960;
    srcs[1] = y1h + (size_t)(img0 + 1) * 28800 + row0 * 960;
    srcs[2] = y1l + (size_t)img0 * 28800 + row0 * 960;
    srcs[3] = y1l + (size_t)(img0 + 1) * 28800 + row0 * 960;
    const int dstb[4] = {0, 5760, 11520, 17280};
#pragma unroll
    for (int seg = 0; seg < 4; ++seg) {
      const _Float16* s = srcs[seg];
      _Float16* d = &S[dstb[seg]];
      for (int c = tid; c < 720; c += 448)
        *(float4*)&d[c * 8] = *(const float4*)&s[c * 8];
    }
  }

  const int w = tid >> 6;
  const int lane = tid & 63;
  const int l31 = lane & 31;
  const int g = lane >> 5;
  const int m = w * 32 + l31;
  const int aimg = m / 112;
  const int apos = m - aimg * 112;
  const int ar = apos / 28;
  const int ax = apos - ar * 28;
  const int icg = g * 8;

  f32x16 acc00 = {}, acc01 = {}, acc10 = {}, acc11 = {};

#pragma unroll 1
  for (int tc = 0; tc < 5; ++tc) {
    __syncthreads();
    // ---- stage W chunk: linear copies from packed buffer ----
    const int tap0 = tc * 2;
    const int ntaps = (tc == 4) ? 1 : 2;
    for (int c = tid; c < ntaps * 256; c += 448) {
      *(float4*)&S[23040 + c * 8] = *(const float4*)&w2p[tap0 * 2048 + c * 8];
      *(float4*)&S[27136 + c * 8] =
          *(const float4*)&w2p[18432 + tap0 * 2048 + c * 8];
    }
    __syncthreads();
#pragma unroll 1
    for (int tl = 0; tl < ntaps; ++tl) {
      const int tap = tap0 + tl;
      const int ky = tap / 3;
      const int kx = tap - ky * 3;
      const int acol = ax + kx;
      const int swzA = ((acol >> 1) & 3) << 3;
      const int abase = aimg * 5760 + ((ar + ky) * 30 + acol) * 32;
#pragma unroll
      for (int s = 0; s < 2; ++s) {
        const int icoA = (s * 16 + icg) ^ swzA;
        const int bo0 = 23040 + (((tl * 2 + 0) * 2 + s) * 2 + g) * 256 + l31 * 8;
        const int bo1 = 23040 + (((tl * 2 + 1) * 2 + s) * 2 + g) * 256 + l31 * 8;
        half8 ah = *(const half8*)&S[abase + icoA];
        half8 al = *(const half8*)&S[11520 + abase + icoA];
        half8 bh0 = *(const half8*)&S[bo0];
        half8 bl0 = *(const half8*)&S[bo0 + 4096];
        half8 bh1 = *(const half8*)&S[bo1];
        half8 bl1 = *(const half8*)&S[bo1 + 4096];
        acc00 = __builtin_amdgcn_mfma_f32_32x32x16_f16(ah, bh0, acc00, 0, 0, 0);
        acc10 = __builtin_amdgcn_mfma_f32_32x32x16_f16(ah, bl0, acc10, 0, 0, 0);
        acc10 = __builtin_amdgcn_mfma_f32_32x32x16_f16(al, bh0, acc10, 0, 0, 0);
        acc01 = __builtin_amdgcn_mfma_f32_32x32x16_f16(ah, bh1, acc01, 0, 0, 0);
        acc11 = __builtin_amdgcn_mfma_f32_32x32x16_f16(ah, bl1, acc11, 0, 0, 0);
        acc11 = __builtin_amdgcn_mfma_f32_32x32x16_f16(al, bh1, acc11, 0, 0, 0);
      }
    }
  }
  __syncthreads();
  // ---- conv outputs -> padded LDS pool buffer ----
  float* sPool = (float*)S;  // [224 pos][65]
#pragma unroll
  for (int r = 0; r < 16; ++r) {
    const int mrow = (r & 3) + 8 * (r >> 2) + 4 * g;
    const int mo = w * 32 + mrow;
    sPool[mo * 65 + l31] = acc00[r] + acc10[r] * 9.765625e-4f;
    sPool[mo * 65 + 32 + l31] = acc01[r] + acc11[r] * 9.765625e-4f;
  }
  __syncthreads();
  // ---- bias + relu + 2x2 maxpool + store (FIX: pool over POSITIONS) ----
  for (int idx = tid; idx < 3584; idx += 448) {
    const int img = idx / 1792;
    int rem = idx - img * 1792;
    const int och = rem / 28;
    rem -= och * 28;
    const int pr = rem / 14;
    const int pc = rem - pr * 14;
    const int mb = img * 112 + pr * 56 + pc * 2;
    const float a = sPool[mb * 65 + och];
    const float b = sPool[(mb + 1) * 65 + och];
    const float c = sPool[(mb + 28) * 65 + och];
    const float d = sPool[(mb + 29) * 65 + och];
    const float mx = fmaxf(fmaxf(a, b), fmaxf(c, d));
    y2p[((size_t)(img0 + img) * 64 + och) * 196 + (rp * 2 + pr) * 14 + pc] =
        fmaxf(mx + b2[och], 0.f);
  }
}

// ---------------------------------------------------------------------------
// conv3 via MFMA split-f16 implicit GEMM (W-stage writes ic-fastest).
// ---------------------------------------------------------------------------
__global__ __launch_bounds__(320) void conv3_mfma_k(
    const float* __restrict__ y2p, const float* __restrict__ w3,
    const float* __restrict__ b3, float* __restrict__ feats) {
  __shared__ __align__(16) _Float16 S[24832];
  const int img = blockIdx.x;
  const int tid = threadIdx.x;
  const int w = tid >> 6;
  const int lane = tid & 63;
  const int l31 = lane & 31;
  const int g = lane >> 5;
  const int m = w * 32 + l31;
  const int mc = (m < 144) ? m : 143;
  const int r = mc / 12, c = mc - (mc / 12) * 12;

  f32x16 acch[3] = {};
  f32x16 accl[3] = {};

  const float* inImg = y2p + (size_t)img * 12544;
#pragma unroll 1
  for (int icc = 0; icc < 2; ++icc) {
    __syncthreads();
    for (int idx = tid; idx < 6272; idx += 320) {
      const int ic = idx & 31;
      const int p = idx >> 5;
      const float v = inImg[(icc * 32 + ic) * 196 + p];
      const _Float16 h = (_Float16)v;
      const _Float16 l = (_Float16)((v - (float)h) * 1024.0f);
      const int o = p * 32 + (ic ^ (((p >> 1) & 3) << 3));
      S[o] = h;
      S[6272 + o] = l;
    }
#pragma unroll 1
    for (int tc = 0; tc < 5; ++tc) {
      __syncthreads();
      const int ntaps = (tc == 4) ? 1 : 2;
      for (int idx = tid; idx < 3072 * ntaps; idx += 320) {
        int ic, tl, och;
        if (ntaps == 2) {
          ic = idx & 31;
          tl = (idx >> 5) & 1;
          och = idx >> 6;
        } else {
          ic = idx & 31;
          tl = 0;
          och = idx >> 5;
        }
        const float v = w3[(size_t)och * 576 + (icc * 32 + ic) * 9 + tc * 2 + tl];
        const _Float16 h = (_Float16)v;
        const _Float16 l = (_Float16)((v - (float)h) * 1024.0f);
        const int nt = och >> 5, n = och & 31;
        const int s = ic >> 4, gg = (ic >> 3) & 1, e = ic & 7;
        const int off = ((((tl * 3 + nt) * 2 + s) * 2 + gg) * 32 + n) * 8 + e;
        S[12544 + off] = h;
        S[18688 + off] = l;
      }
      __syncthreads();
#pragma unroll 1
      for (int tl = 0; tl < ntaps; ++tl) {
        const int tap = tc * 2 + tl;
        const int ky = tap / 3, kx = tap - (tap / 3) * 3;
        const int pix = (r + ky) * 14 + (c + kx);
        const int pswz = (pix >> 1) & 3;
        half8 ah[2], al[2];
#pragma unroll
        for (int s = 0; s < 2; ++s) {
          const int o = pix * 32 + ((s * 2 + g) ^ pswz) * 8;
          ah[s] = *(const half8*)&S[o];
          al[s] = *(const half8*)&S[6272 + o];
        }
#pragma unroll
        for (int nt = 0; nt < 3; ++nt) {
#pragma unroll
          for (int s = 0; s < 2; ++s) {
            const int bo = ((((tl * 3 + nt) * 2 + s) * 2 + g) * 32 + l31) * 8;
            half8 bh = *(const half8*)&S[12544 + bo];
            half8 bl = *(const half8*)&S[18688 + bo];
            acch[nt] =
                __builtin_amdgcn_mfma_f32_32x32x16_f16(ah[s], bh, acch[nt], 0, 0, 0);
            accl[nt] =
                __builtin_amdgcn_mfma_f32_32x32x16_f16(ah[s], bl, accl[nt], 0, 0, 0);
            accl[nt] =
                __builtin_amdgcn_mfma_f32_32x32x16_f16(al[s], bh, accl[nt], 0, 0, 0);
          }
        }
      }
    }
  }
  float* sO = (float*)S;
  float* outImg = feats + (size_t)img * 13824;
#pragma unroll
  for (int nt = 0; nt < 3; ++nt) {
    __syncthreads();
#pragma unroll
    for (int rr = 0; rr < 16; ++rr) {
      const int row = (rr & 3) + 8 * (rr >> 2) + 4 * g;
      const int pos = w * 32 + row;
      if (pos < 144)
        sO[l31 * 145 + pos] = acch[nt][rr] + accl[nt][rr] * 9.765625e-4f;
    }
    __syncthreads();
    for (int idx = tid; idx < 4608; idx += 320) {
      const int oc = idx / 144;
      const int pos = idx - oc * 144;
      outImg[(nt * 32 + oc) * 144 + pos] =
          fmaxf(sO[oc * 145 + pos] + b3[nt * 32 + oc], 0.f);
    }
  }
}

// ---------------------------------------------------------------------------
// ff GEMM (chunked): featsc [Cl,13824] x w_in[128,13824]^T -> P[8][2048][128]
// ---------------------------------------------------------------------------
__global__ __launch_bounds__(256) void ffgemm_k(
    const float* __restrict__ A, const float* __restrict__ Bw,
    float* __restrict__ P, int frame0, int Cl) {
  __shared__ float sA[32 * 64];
  __shared__ float sB[32 * 128];
  const int mb = blockIdx.x;
  const int kc = blockIdx.y;
  const int tid = threadIdx.x;
  const int tm = tid >> 4, tn = tid & 15;
  const int m0 = tm * 4, n0 = tn * 8;
  float acc[4][8];
#pragma unroll
  for (int m = 0; m < 4; ++m)
#pragma unroll
    for (int n = 0; n < 8; ++n) acc[m][n] = 0.f;
  const int kbase = kc * 1728;
  for (int kt = 0; kt < 1728; kt += 32) {
    __syncthreads();
#pragma unroll
    for (int i = 0; i < 2; ++i) {
      int idx = tid + i * 256;
      int row = idx >> 3, kq = idx & 7;
      int rowc = mb * 64 + row;
      if (rowc >= Cl) rowc = Cl - 1;
      float4 v = *(const float4*)(A + (size_t)rowc * 13824 + kbase + kt + kq * 4);
      sA[(kq * 4 + 0) * 64 + row] = v.x;
      sA[(kq * 4 + 1) * 64 + row] = v.y;
      sA[(kq * 4 + 2) * 64 + row] = v.z;
      sA[(kq * 4 + 3) * 64 + row] = v.w;
    }
#pragma unroll
    for (int i = 0; i < 4; ++i) {
      int idx = tid + i * 256;
      int n = idx >> 3, kq = idx & 7;
      float4 v = *(const float4*)(Bw + (size_t)n * 13824 + kbase + kt + kq * 4);
      sB[(kq * 4 + 0) * 128 + n] = v.x;
      sB[(kq * 4 + 1) * 128 + n] = v.y;
      sB[(kq * 4 + 2) * 128 + n] = v.z;
      sB[(kq * 4 + 3) * 128 + n] = v.w;
    }
    __syncthreads();
#pragma unroll
    for (int k = 0; k < 32; ++k) {
      float a4[4], b8[8];
      *(float4*)a4 = *(const float4*)&sA[k * 64 + m0];
      *(float4*)(b8) = *(const float4*)&sB[k * 128 + n0];
      *(float4*)(b8 + 4) = *(const float4*)&sB[k * 128 + n0 + 4];
#pragma unroll
      for (int m = 0; m < 4; ++m)
#pragma unroll
        for (int n = 0; n < 8; ++n) acc[m][n] += a4[m] * b8[n];
    }
  }
  float* Pp = P + ((size_t)kc * 2048 + (size_t)frame0 + (size_t)mb * 64) * 128;
#pragma unroll
  for (int m = 0; m < 4; ++m) {
    if (mb * 64 + m0 + m < Cl) {
      *(float4*)&Pp[(m0 + m) * 128 + n0] = *(float4*)&acc[m][0];
      *(float4*)&Pp[(m0 + m) * 128 + n0 + 4] = *(float4*)&acc[m][4];
    }
  }
}

__global__ __launch_bounds__(256) void ffreduce_k(const float* __restrict__ P,
                                                  float* __restrict__ ffo) {
  const int i = blockIdx.x * 256 + threadIdx.x;
  float s = 0.f;
#pragma unroll
  for (int kcc = 0; kcc < 8; ++kcc) s += P[(size_t)kcc * 262144 + i];
  ffo[i] = s;
}

// ---------------------------------------------------------------------------
// Recurrent LIF scan (unchanged)
// ---------------------------------------------------------------------------
__global__ __launch_bounds__(64) void scan_k(
    const float* __restrict__ ff, const float* __restrict__ w_rec,
    const float* __restrict__ w_fc, const float* __restrict__ b_fc,
    float* __restrict__ out) {
#pragma clang fp contract(off)
  __shared__ float sWr[16384];
  const int b = blockIdx.x;
  const int t = threadIdx.x;
  for (int idx = t; idx < 16384; idx += 64) {
    int hh = idx >> 7, j = idx & 127;
    sWr[j * 128 + hh] = w_rec[idx];
  }
  float wf0[10], wf1[10], bf[10];
#pragma unroll
  for (int c = 0; c < 10; ++c) {
    wf0[c] = w_fc[c * 128 + t];
    wf1[c] = w_fc[c * 128 + 64 + t];
    bf[c] = b_fc[c];
  }
  __syncthreads();
  float v0 = 0.f, v1 = 0.f, i0 = 0.f, i1 = 0.f;
  float vr[10], ir[10], vmax[10];
#pragma unroll
  for (int c = 0; c < 10; ++c) {
    vr[c] = 0.f;
    ir[c] = 0.f;
    vmax[c] = -1e30f;
  }
  unsigned long long pm0 = 0ull, pm1 = 0ull;
  const float* ffb = ff + (size_t)b * 8192;
#pragma unroll 1
  for (int ts = 0; ts < 64; ++ts) {
    const float vd0 = v0 + 0.1f * (i0 - v0);
    const float vd1 = v1 + 0.1f * (i1 - v1);
    const float id0 = i0 - 0.2f * i0;
    const float id1 = i1 - 0.2f * i1;
    const bool z0 = (vd0 - 0.4f) > 0.f;
    const bool z1 = (vd1 - 0.4f) > 0.f;
    v0 = z0 ? 0.f : vd0;
    v1 = z1 ? 0.f : vd1;
    float rec0 = 0.f, rec1 = 0.f;
    unsigned long long mm = pm0;
    while (mm) {
      int j = __ffsll(mm) - 1;
      mm &= mm - 1;
      rec0 += sWr[j * 128 + t];
      rec1 += sWr[j * 128 + t + 64];
    }
    mm = pm1;
    while (mm) {
      int j = __ffsll(mm) - 1;
      mm &= mm - 1;
      rec0 += sWr[(j + 64) * 128 + t];
      rec1 += sWr[(j + 64) * 128 + t + 64];
    }
    i0 = (id0 + ffb[ts * 128 + t]) + rec0;
    i1 = (id1 + ffb[ts * 128 + 64 + t]) + rec1;
    pm0 = __ballot(z0);
    pm1 = __ballot(z1);
#pragma unroll
    for (int c = 0; c < 10; ++c) {
      float val = (z0 ? wf0[c] : 0.f) + (z1 ? wf1[c] : 0.f);
      val += __shfl_xor(val, 1);
      val += __shfl_xor(val, 2);
      val += __shfl_xor(val, 4);
      val += __shfl_xor(val, 8);
      val += __shfl_xor(val, 16);
      val += __shfl_xor(val, 32);
      const float ro = val + bf[c];
      vr[c] = vr[c] + 0.1f * (ir[c] - vr[c]);
      vmax[c] = fmaxf(vmax[c], vr[c]);
      ir[c] = (ir[c] - 0.2f * ir[c]) + ro;
    }
  }
  if (t == 0) {
    float M = vmax[0];
#pragma unroll
    for (int c = 1; c < 10; ++c) M = fmaxf(M, vmax[c]);
    float s = 0.f;
#pragma unroll
    for (int c = 0; c < 10; ++c) s += expf(vmax[c] - M);
    const float ls = logf(s);
#pragma unroll
    for (int c = 0; c < 10; ++c) out[b * 10 + c] = vmax[c] - M - ls;
  }
}

// ---------------------------------------------------------------------------
extern "C" void kernel_launch(void* const* d_in, const int* in_sizes, int n_in,
                              void* d_out, int out_size, void* d_ws,
                              size_t ws_size, hipStream_t stream) {
  (void)in_sizes;
  (void)n_in;
  (void)out_size;
  const float* x = (const float*)d_in[0];
  const float* w1 = (const float*)d_in[1];
  const float* b1 = (const float*)d_in[2];
  const float* w2 = (const float*)d_in[3];
  const float* b2 = (const float*)d_in[4];
  const float* w3 = (const float*)d_in[5];
  const float* b3 = (const float*)d_in[6];
  const float* w_in = (const float*)d_in[7];
  const float* w_rec = (const float*)d_in[8];
  const float* w_fc = (const float*)d_in[9];
  const float* b_fc = (const float*)d_in[10];
  float* out = (float*)d_out;
  char* ws = (char*)d_ws;

  // workspace: ff (1MB) | P (8MB) | w2p (144KB) | per-chunk {y1h,y1l,y2c,fc}
  const size_t HDR = 1048576ull + 8388608ull + 147456ull;  // 9,584,640
  const size_t PERF = 115200ull + 50176ull + 55296ull;     // 220,672
  int C = 32;
  for (int c = 2048; c >= 32; c >>= 1) {
    if (HDR + (size_t)c * PERF <= ws_size) { C = c; break; }
  }
  float* ffbuf = (float*)ws;
  float* P = (float*)(ws + 1048576ull);
  _Float16* w2p = (_Float16*)(ws + 1048576ull + 8388608ull);
  _Float16* y1h = (_Float16*)(ws + HDR);
  _Float16* y1l = y1h + (size_t)C * 28800;
  float* y2c = (float*)(ws + HDR + (size_t)C * 115200ull);
  float* fc = y2c + (size_t)C * 12544;

  w2prep_k<<<72, 256, 0, stream>>>(w2, w2p);

  const int nChunks = 2048 / C;
  const int mbN = (C + 63) / 64;
  for (int ch = 0; ch < nChunks; ++ch) {
    const int f0 = ch * C;
    conv1_k<<<C, 256, 0, stream>>>(x + (size_t)f0 * 4096, w1, b1, y1h, y1l);
    conv2_mfma_k<<<dim3(7, C / 2), 448, 0, stream>>>(y1h, y1l, w2p, b2, y2c);
    conv3_mfma_k<<<C, 320, 0, stream>>>(y2c, w3, b3, fc);
    ffgemm_k<<<dim3(mbN, 8), 256, 0, stream>>>(fc, w_in, P, f0, C);
  }
  ffreduce_k<<<1024, 256, 0, stream>>>(P, ffbuf);
  scan_k<<<32, 64, 0, stream>>>(ffbuf, w_rec, w_fc, b_fc, out);
}

// Round 7
// 1234.374 us; speedup vs baseline: 1.8655x; 1.8655x over previous
//
#include <hip/hip_runtime.h>
#include <math.h>

typedef _Float16 half8 __attribute__((ext_vector_type(8)));
typedef float f32x16 __attribute__((ext_vector_type(16)));

// ---------------------------------------------------------------------------
// w2prep: pack w2 [64,32,3,3] into MFMA-fragment order, split hi/lo f16.
// w2p layout: hi plane [tap 9][blk 8][n 32][e 8] (18432), then lo plane.
//   blk = nt*4 + s*2 + g ; och = nt*32+n ; ic = s*16+g*8+e
// ---------------------------------------------------------------------------
__global__ __launch_bounds__(256) void w2prep_k(const float* __restrict__ w2,
                                                _Float16* __restrict__ w2p) {
  const int i = blockIdx.x * 256 + threadIdx.x;
  if (i >= 18432) return;
  const int tap = i >> 11;
  const int r = i & 2047;
  const int blk = r >> 8;
  const int nt = blk >> 2, s = (blk >> 1) & 1, g = blk & 1;
  const int n = (r >> 3) & 31, e = r & 7;
  const int och = nt * 32 + n;
  const int ic = s * 16 + g * 8 + e;
  const float v = w2[och * 288 + ic * 9 + tap];
  const _Float16 h = (_Float16)v;
  const _Float16 l = (_Float16)((v - (float)h) * 1024.0f);
  w2p[i] = h;
  w2p[18432 + i] = l;
}

// ---------------------------------------------------------------------------
// conv1: x [C,1,64,64] -> y1h/y1l [C][900 pos][32 ic^swz] f16 (split, NHWC,
// pre-swizzled: ch-block gb stored at slot gb ^ ((col>>1)&3)).
// v3: channel-group-of-8 accumulation to kill VGPR spills (R6: 256 VGPR,
// 565 MB scratch reads). Live set ~90 VGPRs.
// ---------------------------------------------------------------------------
__global__ __launch_bounds__(256) void conv1_k(
    const float* __restrict__ x, const float* __restrict__ w1,
    const float* __restrict__ b1, _Float16* __restrict__ y1h,
    _Float16* __restrict__ y1l) {
  __shared__ float sIn[4096];
  __shared__ float sW[32 * 28];
  __shared__ float sB[32];
  const int img = blockIdx.x;
  const int tid = threadIdx.x;
  {
    const float4* src = (const float4*)(x + (size_t)img * 4096);
    float4* dst = (float4*)sIn;
#pragma unroll
    for (int i = 0; i < 4; ++i) dst[tid + i * 256] = src[tid + i * 256];
  }
  for (int i = tid; i < 800; i += 256) {
    int ch = i / 25, k = i % 25;
    sW[ch * 28 + k] = w1[i];
  }
  if (tid < 32) sB[tid] = b1[tid];
  __syncthreads();
  _Float16* oh = y1h + (size_t)img * 28800;
  _Float16* ol = y1l + (size_t)img * 28800;
#pragma unroll 1
  for (int it = 0; it < 2; ++it) {
    const int p0 = tid + it * 512;
    const int p1 = p0 + 256;
    const bool v1 = (p1 < 900);
    const int q1 = v1 ? p1 : 0;
    const int oy0 = p0 / 30, ox0 = p0 % 30;
    const int oy1 = q1 / 30, ox1 = q1 % 30;
    float a0[25], a1[25];
#pragma unroll
    for (int ky = 0; ky < 5; ++ky)
#pragma unroll
      for (int kx = 0; kx < 5; ++kx) {
        a0[ky * 5 + kx] = sIn[(2 * oy0 + ky) * 64 + 2 * ox0 + kx];
        a1[ky * 5 + kx] = sIn[(2 * oy1 + ky) * 64 + 2 * ox1 + kx];
      }
    const int swz0 = (ox0 >> 1) & 3;
    const int swz1 = (ox1 >> 1) & 3;
#pragma unroll 1
    for (int gb = 0; gb < 4; ++gb) {
      float acc0[8], acc1[8];
#pragma unroll
      for (int e = 0; e < 8; ++e) {
        const int ch = gb * 8 + e;
        float s0 = 0.f, s1 = 0.f;
#pragma unroll
        for (int k = 0; k < 25; ++k) {
          const float w = sW[ch * 28 + k];
          s0 += w * a0[k];
          s1 += w * a1[k];
        }
        acc0[e] = fmaxf(s0 + sB[ch], 0.f);
        acc1[e] = fmaxf(s1 + sB[ch], 0.f);
      }
      half8 h0, l0;
#pragma unroll
      for (int e = 0; e < 8; ++e) {
        const _Float16 hh = (_Float16)acc0[e];
        h0[e] = hh;
        l0[e] = (_Float16)((acc0[e] - (float)hh) * 1024.0f);
      }
      *(float4*)&oh[p0 * 32 + (gb ^ swz0) * 8] = *(float4*)&h0;
      *(float4*)&ol[p0 * 32 + (gb ^ swz0) * 8] = *(float4*)&l0;
      if (v1) {
        half8 h1, l1;
#pragma unroll
        for (int e = 0; e < 8; ++e) {
          const _Float16 hh = (_Float16)acc1[e];
          h1[e] = hh;
          l1[e] = (_Float16)((acc1[e] - (float)hh) * 1024.0f);
        }
        *(float4*)&oh[p1 * 32 + (gb ^ swz1) * 8] = *(float4*)&h1;
        *(float4*)&ol[p1 * 32 + (gb ^ swz1) * 8] = *(float4*)&l1;
      }
    }
  }
}

// ---------------------------------------------------------------------------
// conv2 + maxpool, MFMA split-f16 implicit GEMM (unchanged from R6 PASS).
// ---------------------------------------------------------------------------
__global__ __launch_bounds__(448) void conv2_mfma_k(
    const _Float16* __restrict__ y1h, const _Float16* __restrict__ y1l,
    const _Float16* __restrict__ w2p, const float* __restrict__ b2,
    float* __restrict__ y2p) {
  __shared__ __align__(16) _Float16 S[31232];
  const int rp = blockIdx.x;
  const int img0 = blockIdx.y * 2;
  const int tid = threadIdx.x;
  const int row0 = rp * 4;

  {
    const _Float16* srcs[4];
    srcs[0] = y1h + (size_t)img0 * 28800 + row0 * 960;
    srcs[1] = y1h + (size_t)(img0 + 1) * 28800 + row0 * 960;
    srcs[2] = y1l + (size_t)img0 * 28800 + row0 * 960;
    srcs[3] = y1l + (size_t)(img0 + 1) * 28800 + row0 * 960;
    const int dstb[4] = {0, 5760, 11520, 17280};
#pragma unroll
    for (int seg = 0; seg < 4; ++seg) {
      const _Float16* s = srcs[seg];
      _Float16* d = &S[dstb[seg]];
      for (int c = tid; c < 720; c += 448)
        *(float4*)&d[c * 8] = *(const float4*)&s[c * 8];
    }
  }

  const int w = tid >> 6;
  const int lane = tid & 63;
  const int l31 = lane & 31;
  const int g = lane >> 5;
  const int m = w * 32 + l31;
  const int aimg = m / 112;
  const int apos = m - aimg * 112;
  const int ar = apos / 28;
  const int ax = apos - ar * 28;
  const int icg = g * 8;

  f32x16 acc00 = {}, acc01 = {}, acc10 = {}, acc11 = {};

#pragma unroll 1
  for (int tc = 0; tc < 5; ++tc) {
    __syncthreads();
    const int tap0 = tc * 2;
    const int ntaps = (tc == 4) ? 1 : 2;
    for (int c = tid; c < ntaps * 256; c += 448) {
      *(float4*)&S[23040 + c * 8] = *(const float4*)&w2p[tap0 * 2048 + c * 8];
      *(float4*)&S[27136 + c * 8] =
          *(const float4*)&w2p[18432 + tap0 * 2048 + c * 8];
    }
    __syncthreads();
#pragma unroll 1
    for (int tl = 0; tl < ntaps; ++tl) {
      const int tap = tap0 + tl;
      const int ky = tap / 3;
      const int kx = tap - ky * 3;
      const int acol = ax + kx;
      const int swzA = ((acol >> 1) & 3) << 3;
      const int abase = aimg * 5760 + ((ar + ky) * 30 + acol) * 32;
#pragma unroll
      for (int s = 0; s < 2; ++s) {
        const int icoA = (s * 16 + icg) ^ swzA;
        const int bo0 = 23040 + (((tl * 2 + 0) * 2 + s) * 2 + g) * 256 + l31 * 8;
        const int bo1 = 23040 + (((tl * 2 + 1) * 2 + s) * 2 + g) * 256 + l31 * 8;
        half8 ah = *(const half8*)&S[abase + icoA];
        half8 al = *(const half8*)&S[11520 + abase + icoA];
        half8 bh0 = *(const half8*)&S[bo0];
        half8 bl0 = *(const half8*)&S[bo0 + 4096];
        half8 bh1 = *(const half8*)&S[bo1];
        half8 bl1 = *(const half8*)&S[bo1 + 4096];
        acc00 = __builtin_amdgcn_mfma_f32_32x32x16_f16(ah, bh0, acc00, 0, 0, 0);
        acc10 = __builtin_amdgcn_mfma_f32_32x32x16_f16(ah, bl0, acc10, 0, 0, 0);
        acc10 = __builtin_amdgcn_mfma_f32_32x32x16_f16(al, bh0, acc10, 0, 0, 0);
        acc01 = __builtin_amdgcn_mfma_f32_32x32x16_f16(ah, bh1, acc01, 0, 0, 0);
        acc11 = __builtin_amdgcn_mfma_f32_32x32x16_f16(ah, bl1, acc11, 0, 0, 0);
        acc11 = __builtin_amdgcn_mfma_f32_32x32x16_f16(al, bh1, acc11, 0, 0, 0);
      }
    }
  }
  __syncthreads();
  float* sPool = (float*)S;  // [224 pos][65]
#pragma unroll
  for (int r = 0; r < 16; ++r) {
    const int mrow = (r & 3) + 8 * (r >> 2) + 4 * g;
    const int mo = w * 32 + mrow;
    sPool[mo * 65 + l31] = acc00[r] + acc10[r] * 9.765625e-4f;
    sPool[mo * 65 + 32 + l31] = acc01[r] + acc11[r] * 9.765625e-4f;
  }
  __syncthreads();
  for (int idx = tid; idx < 3584; idx += 448) {
    const int img = idx / 1792;
    int rem = idx - img * 1792;
    const int och = rem / 28;
    rem -= och * 28;
    const int pr = rem / 14;
    const int pc = rem - pr * 14;
    const int mb = img * 112 + pr * 56 + pc * 2;
    const float a = sPool[mb * 65 + och];
    const float b = sPool[(mb + 1) * 65 + och];
    const float c = sPool[(mb + 28) * 65 + och];
    const float d = sPool[(mb + 29) * 65 + och];
    const float mx = fmaxf(fmaxf(a, b), fmaxf(c, d));
    y2p[((size_t)(img0 + img) * 64 + och) * 196 + (rp * 2 + pr) * 14 + pc] =
        fmaxf(mx + b2[och], 0.f);
  }
}

// ---------------------------------------------------------------------------
// conv3 via MFMA split-f16 implicit GEMM (unchanged from R6 PASS).
// ---------------------------------------------------------------------------
__global__ __launch_bounds__(320) void conv3_mfma_k(
    const float* __restrict__ y2p, const float* __restrict__ w3,
    const float* __restrict__ b3, float* __restrict__ feats) {
  __shared__ __align__(16) _Float16 S[24832];
  const int img = blockIdx.x;
  const int tid = threadIdx.x;
  const int w = tid >> 6;
  const int lane = tid & 63;
  const int l31 = lane & 31;
  const int g = lane >> 5;
  const int m = w * 32 + l31;
  const int mc = (m < 144) ? m : 143;
  const int r = mc / 12, c = mc - (mc / 12) * 12;

  f32x16 acch[3] = {};
  f32x16 accl[3] = {};

  const float* inImg = y2p + (size_t)img * 12544;
#pragma unroll 1
  for (int icc = 0; icc < 2; ++icc) {
    __syncthreads();
    for (int idx = tid; idx < 6272; idx += 320) {
      const int ic = idx & 31;
      const int p = idx >> 5;
      const float v = inImg[(icc * 32 + ic) * 196 + p];
      const _Float16 h = (_Float16)v;
      const _Float16 l = (_Float16)((v - (float)h) * 1024.0f);
      const int o = p * 32 + (ic ^ (((p >> 1) & 3) << 3));
      S[o] = h;
      S[6272 + o] = l;
    }
#pragma unroll 1
    for (int tc = 0; tc < 5; ++tc) {
      __syncthreads();
      const int ntaps = (tc == 4) ? 1 : 2;
      for (int idx = tid; idx < 3072 * ntaps; idx += 320) {
        int ic, tl, och;
        if (ntaps == 2) {
          ic = idx & 31;
          tl = (idx >> 5) & 1;
          och = idx >> 6;
        } else {
          ic = idx & 31;
          tl = 0;
          och = idx >> 5;
        }
        const float v = w3[(size_t)och * 576 + (icc * 32 + ic) * 9 + tc * 2 + tl];
        const _Float16 h = (_Float16)v;
        const _Float16 l = (_Float16)((v - (float)h) * 1024.0f);
        const int nt = och >> 5, n = och & 31;
        const int s = ic >> 4, gg = (ic >> 3) & 1, e = ic & 7;
        const int off = ((((tl * 3 + nt) * 2 + s) * 2 + gg) * 32 + n) * 8 + e;
        S[12544 + off] = h;
        S[18688 + off] = l;
      }
      __syncthreads();
#pragma unroll 1
      for (int tl = 0; tl < ntaps; ++tl) {
        const int tap = tc * 2 + tl;
        const int ky = tap / 3, kx = tap - (tap / 3) * 3;
        const int pix = (r + ky) * 14 + (c + kx);
        const int pswz = (pix >> 1) & 3;
        half8 ah[2], al[2];
#pragma unroll
        for (int s = 0; s < 2; ++s) {
          const int o = pix * 32 + ((s * 2 + g) ^ pswz) * 8;
          ah[s] = *(const half8*)&S[o];
          al[s] = *(const half8*)&S[6272 + o];
        }
#pragma unroll
        for (int nt = 0; nt < 3; ++nt) {
#pragma unroll
          for (int s = 0; s < 2; ++s) {
            const int bo = ((((tl * 3 + nt) * 2 + s) * 2 + g) * 32 + l31) * 8;
            half8 bh = *(const half8*)&S[12544 + bo];
            half8 bl = *(const half8*)&S[18688 + bo];
            acch[nt] =
                __builtin_amdgcn_mfma_f32_32x32x16_f16(ah[s], bh, acch[nt], 0, 0, 0);
            accl[nt] =
                __builtin_amdgcn_mfma_f32_32x32x16_f16(ah[s], bl, accl[nt], 0, 0, 0);
            accl[nt] =
                __builtin_amdgcn_mfma_f32_32x32x16_f16(al[s], bh, accl[nt], 0, 0, 0);
          }
        }
      }
    }
  }
  float* sO = (float*)S;
  float* outImg = feats + (size_t)img * 13824;
#pragma unroll
  for (int nt = 0; nt < 3; ++nt) {
    __syncthreads();
#pragma unroll
    for (int rr = 0; rr < 16; ++rr) {
      const int row = (rr & 3) + 8 * (rr >> 2) + 4 * g;
      const int pos = w * 32 + row;
      if (pos < 144)
        sO[l31 * 145 + pos] = acch[nt][rr] + accl[nt][rr] * 9.765625e-4f;
    }
    __syncthreads();
    for (int idx = tid; idx < 4608; idx += 320) {
      const int oc = idx / 144;
      const int pos = idx - oc * 144;
      outImg[(nt * 32 + oc) * 144 + pos] =
          fmaxf(sO[oc * 145 + pos] + b3[nt * 32 + oc], 0.f);
    }
  }
}

// ---------------------------------------------------------------------------
// ff GEMM (chunked): featsc [Cl,13824] x w_in[128,13824]^T -> P[8][2048][128]
// ---------------------------------------------------------------------------
__global__ __launch_bounds__(256) void ffgemm_k(
    const float* __restrict__ A, const float* __restrict__ Bw,
    float* __restrict__ P, int frame0, int Cl) {
  __shared__ float sA[32 * 64];
  __shared__ float sB[32 * 128];
  const int mb = blockIdx.x;
  const int kc = blockIdx.y;
  const int tid = threadIdx.x;
  const int tm = tid >> 4, tn = tid & 15;
  const int m0 = tm * 4, n0 = tn * 8;
  float acc[4][8];
#pragma unroll
  for (int m = 0; m < 4; ++m)
#pragma unroll
    for (int n = 0; n < 8; ++n) acc[m][n] = 0.f;
  const int kbase = kc * 1728;
  for (int kt = 0; kt < 1728; kt += 32) {
    __syncthreads();
#pragma unroll
    for (int i = 0; i < 2; ++i) {
      int idx = tid + i * 256;
      int row = idx >> 3, kq = idx & 7;
      int rowc = mb * 64 + row;
      if (rowc >= Cl) rowc = Cl - 1;
      float4 v = *(const float4*)(A + (size_t)rowc * 13824 + kbase + kt + kq * 4);
      sA[(kq * 4 + 0) * 64 + row] = v.x;
      sA[(kq * 4 + 1) * 64 + row] = v.y;
      sA[(kq * 4 + 2) * 64 + row] = v.z;
      sA[(kq * 4 + 3) * 64 + row] = v.w;
    }
#pragma unroll
    for (int i = 0; i < 4; ++i) {
      int idx = tid + i * 256;
      int n = idx >> 3, kq = idx & 7;
      float4 v = *(const float4*)(Bw + (size_t)n * 13824 + kbase + kt + kq * 4);
      sB[(kq * 4 + 0) * 128 + n] = v.x;
      sB[(kq * 4 + 1) * 128 + n] = v.y;
      sB[(kq * 4 + 2) * 128 + n] = v.z;
      sB[(kq * 4 + 3) * 128 + n] = v.w;
    }
    __syncthreads();
#pragma unroll
    for (int k = 0; k < 32; ++k) {
      float a4[4], b8[8];
      *(float4*)a4 = *(const float4*)&sA[k * 64 + m0];
      *(float4*)(b8) = *(const float4*)&sB[k * 128 + n0];
      *(float4*)(b8 + 4) = *(const float4*)&sB[k * 128 + n0 + 4];
#pragma unroll
      for (int m = 0; m < 4; ++m)
#pragma unroll
        for (int n = 0; n < 8; ++n) acc[m][n] += a4[m] * b8[n];
    }
  }
  float* Pp = P + ((size_t)kc * 2048 + (size_t)frame0 + (size_t)mb * 64) * 128;
#pragma unroll
  for (int m = 0; m < 4; ++m) {
    if (mb * 64 + m0 + m < Cl) {
      *(float4*)&Pp[(m0 + m) * 128 + n0] = *(float4*)&acc[m][0];
      *(float4*)&Pp[(m0 + m) * 128 + n0 + 4] = *(float4*)&acc[m][4];
    }
  }
}

__global__ __launch_bounds__(256) void ffreduce_k(const float* __restrict__ P,
                                                  float* __restrict__ ffo) {
  const int i = blockIdx.x * 256 + threadIdx.x;
  float s = 0.f;
#pragma unroll
  for (int kcc = 0; kcc < 8; ++kcc) s += P[(size_t)kcc * 262144 + i];
  ffo[i] = s;
}

// ---------------------------------------------------------------------------
// Recurrent LIF scan (unchanged)
// ---------------------------------------------------------------------------
__global__ __launch_bounds__(64) void scan_k(
    const float* __restrict__ ff, const float* __restrict__ w_rec,
    const float* __restrict__ w_fc, const float* __restrict__ b_fc,
    float* __restrict__ out) {
#pragma clang fp contract(off)
  __shared__ float sWr[16384];
  const int b = blockIdx.x;
  const int t = threadIdx.x;
  for (int idx = t; idx < 16384; idx += 64) {
    int hh = idx >> 7, j = idx & 127;
    sWr[j * 128 + hh] = w_rec[idx];
  }
  float wf0[10], wf1[10], bf[10];
#pragma unroll
  for (int c = 0; c < 10; ++c) {
    wf0[c] = w_fc[c * 128 + t];
    wf1[c] = w_fc[c * 128 + 64 + t];
    bf[c] = b_fc[c];
  }
  __syncthreads();
  float v0 = 0.f, v1 = 0.f, i0 = 0.f, i1 = 0.f;
  float vr[10], ir[10], vmax[10];
#pragma unroll
  for (int c = 0; c < 10; ++c) {
    vr[c] = 0.f;
    ir[c] = 0.f;
    vmax[c] = -1e30f;
  }
  unsigned long long pm0 = 0ull, pm1 = 0ull;
  const float* ffb = ff + (size_t)b * 8192;
#pragma unroll 1
  for (int ts = 0; ts < 64; ++ts) {
    const float vd0 = v0 + 0.1f * (i0 - v0);
    const float vd1 = v1 + 0.1f * (i1 - v1);
    const float id0 = i0 - 0.2f * i0;
    const float id1 = i1 - 0.2f * i1;
    const bool z0 = (vd0 - 0.4f) > 0.f;
    const bool z1 = (vd1 - 0.4f) > 0.f;
    v0 = z0 ? 0.f : vd0;
    v1 = z1 ? 0.f : vd1;
    float rec0 = 0.f, rec1 = 0.f;
    unsigned long long mm = pm0;
    while (mm) {
      int j = __ffsll(mm) - 1;
      mm &= mm - 1;
      rec0 += sWr[j * 128 + t];
      rec1 += sWr[j * 128 + t + 64];
    }
    mm = pm1;
    while (mm) {
      int j = __ffsll(mm) - 1;
      mm &= mm - 1;
      rec0 += sWr[(j + 64) * 128 + t];
      rec1 += sWr[(j + 64) * 128 + t + 64];
    }
    i0 = (id0 + ffb[ts * 128 + t]) + rec0;
    i1 = (id1 + ffb[ts * 128 + 64 + t]) + rec1;
    pm0 = __ballot(z0);
    pm1 = __ballot(z1);
#pragma unroll
    for (int c = 0; c < 10; ++c) {
      float val = (z0 ? wf0[c] : 0.f) + (z1 ? wf1[c] : 0.f);
      val += __shfl_xor(val, 1);
      val += __shfl_xor(val, 2);
      val += __shfl_xor(val, 4);
      val += __shfl_xor(val, 8);
      val += __shfl_xor(val, 16);
      val += __shfl_xor(val, 32);
      const float ro = val + bf[c];
      vr[c] = vr[c] + 0.1f * (ir[c] - vr[c]);
      vmax[c] = fmaxf(vmax[c], vr[c]);
      ir[c] = (ir[c] - 0.2f * ir[c]) + ro;
    }
  }
  if (t == 0) {
    float M = vmax[0];
#pragma unroll
    for (int c = 1; c < 10; ++c) M = fmaxf(M, vmax[c]);
    float s = 0.f;
#pragma unroll
    for (int c = 0; c < 10; ++c) s += expf(vmax[c] - M);
    const float ls = logf(s);
#pragma unroll
    for (int c = 0; c < 10; ++c) out[b * 10 + c] = vmax[c] - M - ls;
  }
}

// ---------------------------------------------------------------------------
extern "C" void kernel_launch(void* const* d_in, const int* in_sizes, int n_in,
                              void* d_out, int out_size, void* d_ws,
                              size_t ws_size, hipStream_t stream) {
  (void)in_sizes;
  (void)n_in;
  (void)out_size;
  const float* x = (const float*)d_in[0];
  const float* w1 = (const float*)d_in[1];
  const float* b1 = (const float*)d_in[2];
  const float* w2 = (const float*)d_in[3];
  const float* b2 = (const float*)d_in[4];
  const float* w3 = (const float*)d_in[5];
  const float* b3 = (const float*)d_in[6];
  const float* w_in = (const float*)d_in[7];
  const float* w_rec = (const float*)d_in[8];
  const float* w_fc = (const float*)d_in[9];
  const float* b_fc = (const float*)d_in[10];
  float* out = (float*)d_out;
  char* ws = (char*)d_ws;

  // workspace: ff (1MB) | P (8MB) | w2p (144KB) | per-chunk {y1h,y1l,y2c,fc}
  const size_t HDR = 1048576ull + 8388608ull + 147456ull;  // 9,584,640
  const size_t PERF = 115200ull + 50176ull + 55296ull;     // 220,672
  int C = 32;
  for (int c = 2048; c >= 32; c >>= 1) {
    if (HDR + (size_t)c * PERF <= ws_size) { C = c; break; }
  }
  float* ffbuf = (float*)ws;
  float* P = (float*)(ws + 1048576ull);
  _Float16* w2p = (_Float16*)(ws + 1048576ull + 8388608ull);
  _Float16* y1h = (_Float16*)(ws + HDR);
  _Float16* y1l = y1h + (size_t)C * 28800;
  float* y2c = (float*)(ws + HDR + (size_t)C * 115200ull);
  float* fc = y2c + (size_t)C * 12544;

  w2prep_k<<<72, 256, 0, stream>>>(w2, w2p);

  const int nChunks = 2048 / C;
  const int mbN = (C + 63) / 64;
  for (int ch = 0; ch < nChunks; ++ch) {
    const int f0 = ch * C;
    conv1_k<<<C, 256, 0, stream>>>(x + (size_t)f0 * 4096, w1, b1, y1h, y1l);
    conv2_mfma_k<<<dim3(7, C / 2), 448, 0, stream>>>(y1h, y1l, w2p, b2, y2c);
    conv3_mfma_k<<<C, 320, 0, stream>>>(y2c, w3, b3, fc);
    ffgemm_k<<<dim3(mbN, 8), 256, 0, stream>>>(fc, w_in, P, f0, C);
  }
  ffreduce_k<<<1024, 256, 0, stream>>>(P, ffbuf);
  scan_k<<<32, 64, 0, stream>>>(ffbuf, w_rec, w_fc, b_fc, out);
}

// Round 9
// 1005.065 us; speedup vs baseline: 2.2911x; 1.2282x over previous
//
#include <hip/hip_runtime.h>
#include <math.h>

typedef _Float16 half8 __attribute__((ext_vector_type(8)));
typedef float f32x16 __attribute__((ext_vector_type(16)));

// ---------------------------------------------------------------------------
// w2prep: pack w2 [64,32,3,3] into MFMA-fragment order, split hi/lo f16.
// w2p: hi plane [tap 9][blk 8][n 32][e 8] (18432), then lo plane.
// ---------------------------------------------------------------------------
__global__ __launch_bounds__(256) void w2prep_k(const float* __restrict__ w2,
                                                _Float16* __restrict__ w2p) {
  const int i = blockIdx.x * 256 + threadIdx.x;
  if (i >= 18432) return;
  const int tap = i >> 11;
  const int r = i & 2047;
  const int blk = r >> 8;
  const int nt = blk >> 2, s = (blk >> 1) & 1, g = blk & 1;
  const int n = (r >> 3) & 31, e = r & 7;
  const int och = nt * 32 + n;
  const int ic = s * 16 + g * 8 + e;
  const float v = w2[och * 288 + ic * 9 + tap];
  const _Float16 h = (_Float16)v;
  const _Float16 l = (_Float16)((v - (float)h) * 1024.0f);
  w2p[i] = h;
  w2p[18432 + i] = l;
}

// ---------------------------------------------------------------------------
// w3prep: pack w3 [96,64,3,3] into conv3's fragment-order LDS image.
// Per icc (32-ic chunk): [tc 5]{tl}[nt 3][s 2][g 2][n 32][e 8], 27648 elems.
// hi plane [0,55296), lo plane [55296,110592).
// ---------------------------------------------------------------------------
__global__ __launch_bounds__(256) void w3prep_k(const float* __restrict__ w3,
                                                _Float16* __restrict__ w3p) {
  const int i = blockIdx.x * 256 + threadIdx.x;
  if (i >= 55296) return;
  const int icc = i / 27648;
  const int r1 = i - icc * 27648;
  const int tc = r1 / 6144;          // 0..4 (tc=4 has half size)
  const int rem = r1 - tc * 6144;
  const int tl = rem / 3072;         // 0..1 (0 only for tc=4)
  const int rem2 = rem - tl * 3072;
  const int nt = rem2 >> 10;
  const int s = (rem2 >> 9) & 1;
  const int g = (rem2 >> 8) & 1;
  const int n = (rem2 >> 3) & 31;
  const int e = rem2 & 7;
  const int tap = tc * 2 + tl;
  const int och = nt * 32 + n;
  const int ic = icc * 32 + s * 16 + g * 8 + e;
  const float v = w3[(size_t)och * 576 + ic * 9 + tap];
  const _Float16 h = (_Float16)v;
  const _Float16 l = (_Float16)((v - (float)h) * 1024.0f);
  w3p[i] = h;
  w3p[55296 + i] = l;
}

// ---------------------------------------------------------------------------
// conv1: x [C,1,64,64] -> y1h/y1l [C][900 pos][32 ic^swz] f16 (split, NHWC,
// pre-swizzled). Channel-group-of-8 accumulation (no spills).
// ---------------------------------------------------------------------------
__global__ __launch_bounds__(256) void conv1_k(
    const float* __restrict__ x, const float* __restrict__ w1,
    const float* __restrict__ b1, _Float16* __restrict__ y1h,
    _Float16* __restrict__ y1l) {
  __shared__ float sIn[4096];
  __shared__ float sW[32 * 28];
  __shared__ float sB[32];
  const int img = blockIdx.x;
  const int tid = threadIdx.x;
  {
    const float4* src = (const float4*)(x + (size_t)img * 4096);
    float4* dst = (float4*)sIn;
#pragma unroll
    for (int i = 0; i < 4; ++i) dst[tid + i * 256] = src[tid + i * 256];
  }
  for (int i = tid; i < 800; i += 256) {
    int ch = i / 25, k = i % 25;
    sW[ch * 28 + k] = w1[i];
  }
  if (tid < 32) sB[tid] = b1[tid];
  __syncthreads();
  _Float16* oh = y1h + (size_t)img * 28800;
  _Float16* ol = y1l + (size_t)img * 28800;
#pragma unroll 1
  for (int it = 0; it < 2; ++it) {
    const int p0 = tid + it * 512;
    const int p1 = p0 + 256;
    const bool v1 = (p1 < 900);
    const int q1 = v1 ? p1 : 0;
    const int oy0 = p0 / 30, ox0 = p0 % 30;
    const int oy1 = q1 / 30, ox1 = q1 % 30;
    float a0[25], a1[25];
#pragma unroll
    for (int ky = 0; ky < 5; ++ky)
#pragma unroll
      for (int kx = 0; kx < 5; ++kx) {
        a0[ky * 5 + kx] = sIn[(2 * oy0 + ky) * 64 + 2 * ox0 + kx];
        a1[ky * 5 + kx] = sIn[(2 * oy1 + ky) * 64 + 2 * ox1 + kx];
      }
    const int swz0 = (ox0 >> 1) & 3;
    const int swz1 = (ox1 >> 1) & 3;
#pragma unroll 1
    for (int gb = 0; gb < 4; ++gb) {
      float acc0[8], acc1[8];
#pragma unroll
      for (int e = 0; e < 8; ++e) {
        const int ch = gb * 8 + e;
        float s0 = 0.f, s1 = 0.f;
#pragma unroll
        for (int k = 0; k < 25; ++k) {
          const float w = sW[ch * 28 + k];
          s0 += w * a0[k];
          s1 += w * a1[k];
        }
        acc0[e] = fmaxf(s0 + sB[ch], 0.f);
        acc1[e] = fmaxf(s1 + sB[ch], 0.f);
      }
      half8 h0, l0;
#pragma unroll
      for (int e = 0; e < 8; ++e) {
        const _Float16 hh = (_Float16)acc0[e];
        h0[e] = hh;
        l0[e] = (_Float16)((acc0[e] - (float)hh) * 1024.0f);
      }
      *(float4*)&oh[p0 * 32 + (gb ^ swz0) * 8] = *(float4*)&h0;
      *(float4*)&ol[p0 * 32 + (gb ^ swz0) * 8] = *(float4*)&l0;
      if (v1) {
        half8 h1, l1;
#pragma unroll
        for (int e = 0; e < 8; ++e) {
          const _Float16 hh = (_Float16)acc1[e];
          h1[e] = hh;
          l1[e] = (_Float16)((acc1[e] - (float)hh) * 1024.0f);
        }
        *(float4*)&oh[p1 * 32 + (gb ^ swz1) * 8] = *(float4*)&h1;
        *(float4*)&ol[p1 * 32 + (gb ^ swz1) * 8] = *(float4*)&l1;
      }
    }
  }
}

// ---------------------------------------------------------------------------
// conv2 + maxpool, MFMA split-f16 implicit GEMM, v3.
// Output SPLIT-f16 pre-swizzled NHWC planes for conv3:
//   y2s[img][icc 2][196 pos][32 slot] hi, +12544 lo (25088 halfwords/img).
// Pool staging stride 68 (16B-aligned rows, conflict-free).
// ---------------------------------------------------------------------------
__global__ __launch_bounds__(448) void conv2_mfma_k(
    const _Float16* __restrict__ y1h, const _Float16* __restrict__ y1l,
    const _Float16* __restrict__ w2p, const float* __restrict__ b2,
    _Float16* __restrict__ y2s) {
  __shared__ __align__(16) _Float16 S[31232];
  const int rp = blockIdx.x;
  const int img0 = blockIdx.y * 2;
  const int tid = threadIdx.x;
  const int row0 = rp * 4;

  {
    const _Float16* srcs[4];
    srcs[0] = y1h + (size_t)img0 * 28800 + row0 * 960;
    srcs[1] = y1h + (size_t)(img0 + 1) * 28800 + row0 * 960;
    srcs[2] = y1l + (size_t)img0 * 28800 + row0 * 960;
    srcs[3] = y1l + (size_t)(img0 + 1) * 28800 + row0 * 960;
    const int dstb[4] = {0, 5760, 11520, 17280};
#pragma unroll
    for (int seg = 0; seg < 4; ++seg) {
      const _Float16* s = srcs[seg];
      _Float16* d = &S[dstb[seg]];
      for (int c = tid; c < 720; c += 448)
        *(float4*)&d[c * 8] = *(const float4*)&s[c * 8];
    }
  }

  const int w = tid >> 6;
  const int lane = tid & 63;
  const int l31 = lane & 31;
  const int g = lane >> 5;
  const int m = w * 32 + l31;
  const int aimg = m / 112;
  const int apos = m - aimg * 112;
  const int ar = apos / 28;
  const int ax = apos - ar * 28;
  const int icg = g * 8;

  f32x16 acc00 = {}, acc01 = {}, acc10 = {}, acc11 = {};

#pragma unroll 1
  for (int tc = 0; tc < 5; ++tc) {
    __syncthreads();
    const int tap0 = tc * 2;
    const int ntaps = (tc == 4) ? 1 : 2;
    for (int c = tid; c < ntaps * 256; c += 448) {
      *(float4*)&S[23040 + c * 8] = *(const float4*)&w2p[tap0 * 2048 + c * 8];
      *(float4*)&S[27136 + c * 8] =
          *(const float4*)&w2p[18432 + tap0 * 2048 + c * 8];
    }
    __syncthreads();
#pragma unroll 1
    for (int tl = 0; tl < ntaps; ++tl) {
      const int tap = tap0 + tl;
      const int ky = tap / 3;
      const int kx = tap - ky * 3;
      const int acol = ax + kx;
      const int swzA = ((acol >> 1) & 3) << 3;
      const int abase = aimg * 5760 + ((ar + ky) * 30 + acol) * 32;
#pragma unroll
      for (int s = 0; s < 2; ++s) {
        const int icoA = (s * 16 + icg) ^ swzA;
        const int bo0 = 23040 + (((tl * 2 + 0) * 2 + s) * 2 + g) * 256 + l31 * 8;
        const int bo1 = 23040 + (((tl * 2 + 1) * 2 + s) * 2 + g) * 256 + l31 * 8;
        half8 ah = *(const half8*)&S[abase + icoA];
        half8 al = *(const half8*)&S[11520 + abase + icoA];
        half8 bh0 = *(const half8*)&S[bo0];
        half8 bl0 = *(const half8*)&S[bo0 + 4096];
        half8 bh1 = *(const half8*)&S[bo1];
        half8 bl1 = *(const half8*)&S[bo1 + 4096];
        acc00 = __builtin_amdgcn_mfma_f32_32x32x16_f16(ah, bh0, acc00, 0, 0, 0);
        acc10 = __builtin_amdgcn_mfma_f32_32x32x16_f16(ah, bl0, acc10, 0, 0, 0);
        acc10 = __builtin_amdgcn_mfma_f32_32x32x16_f16(al, bh0, acc10, 0, 0, 0);
        acc01 = __builtin_amdgcn_mfma_f32_32x32x16_f16(ah, bh1, acc01, 0, 0, 0);
        acc11 = __builtin_amdgcn_mfma_f32_32x32x16_f16(ah, bl1, acc11, 0, 0, 0);
        acc11 = __builtin_amdgcn_mfma_f32_32x32x16_f16(al, bh1, acc11, 0, 0, 0);
      }
    }
  }
  __syncthreads();
  float* sPool = (float*)S;  // [224 pos][68] = 60928 B
#pragma unroll
  for (int r = 0; r < 16; ++r) {
    const int mrow = (r & 3) + 8 * (r >> 2) + 4 * g;
    const int mo = w * 32 + mrow;
    sPool[mo * 68 + l31] = acc00[r] + acc10[r] * 9.765625e-4f;
    sPool[mo * 68 + 32 + l31] = acc01[r] + acc11[r] * 9.765625e-4f;
  }
  __syncthreads();
  // ---- pool + bias + relu + split-f16 NHWC store: 1 task per thread ----
  {
    const int img = tid / 224;
    const int r1 = tid - img * 224;
    const int pr = r1 / 112;
    const int r2 = r1 - pr * 112;
    const int pc = r2 >> 3;
    const int blk = r2 & 7;
    const int m00 = img * 112 + pr * 56 + pc * 2;
    const float* s0 = &sPool[m00 * 68 + blk * 8];
    float rowv[4][8];
    *(float4*)&rowv[0][0] = *(const float4*)s0;
    *(float4*)&rowv[0][4] = *(const float4*)(s0 + 4);
    *(float4*)&rowv[1][0] = *(const float4*)(s0 + 68);
    *(float4*)&rowv[1][4] = *(const float4*)(s0 + 72);
    *(float4*)&rowv[2][0] = *(const float4*)(s0 + 28 * 68);
    *(float4*)&rowv[2][4] = *(const float4*)(s0 + 28 * 68 + 4);
    *(float4*)&rowv[3][0] = *(const float4*)(s0 + 29 * 68);
    *(float4*)&rowv[3][4] = *(const float4*)(s0 + 29 * 68 + 4);
    half8 hv, lv;
#pragma unroll
    for (int e = 0; e < 8; ++e) {
      const float mx =
          fmaxf(fmaxf(rowv[0][e], rowv[1][e]), fmaxf(rowv[2][e], rowv[3][e]));
      const float val = fmaxf(mx + b2[blk * 8 + e], 0.f);
      const _Float16 hh = (_Float16)val;
      hv[e] = hh;
      lv[e] = (_Float16)((val - (float)hh) * 1024.0f);
    }
    const int posg = (rp * 2 + pr) * 14 + pc;
    const int icc = blk >> 2;
    const int slot = (blk & 3) ^ ((posg >> 1) & 3);
    _Float16* dh =
        y2s + (size_t)(img0 + img) * 25088 + icc * 6272 + posg * 32 + slot * 8;
    *(float4*)dh = *(float4*)&hv;
    *(float4*)(dh + 12544) = *(float4*)&lv;
  }
}

// ---------------------------------------------------------------------------
// conv3 via MFMA split-f16 implicit GEMM, v2: all staging is linear float4
// copies from pre-packed producers (y2s + w3p).
// LDS: Xh[0,6272) Xl[6272,12544) Wh[12544,18688) Wl[18688,24832).
// ---------------------------------------------------------------------------
__global__ __launch_bounds__(320) void conv3_mfma_k(
    const _Float16* __restrict__ y2s, const _Float16* __restrict__ w3p,
    const float* __restrict__ b3, float* __restrict__ feats) {
  __shared__ __align__(16) _Float16 S[24832];
  const int img = blockIdx.x;
  const int tid = threadIdx.x;
  const int w = tid >> 6;
  const int lane = tid & 63;
  const int l31 = lane & 31;
  const int g = lane >> 5;
  const int m = w * 32 + l31;
  const int mc = (m < 144) ? m : 143;
  const int r = mc / 12, c = mc - (mc / 12) * 12;

  f32x16 acch[3] = {};
  f32x16 accl[3] = {};

#pragma unroll 1
  for (int icc = 0; icc < 2; ++icc) {
    __syncthreads();
    // ---- stage X: linear copy of pre-split pre-swizzled planes ----
    {
      const _Float16* src = y2s + (size_t)img * 25088 + icc * 6272;
      for (int c8 = tid; c8 < 784; c8 += 320) {
        *(float4*)&S[c8 * 8] = *(const float4*)&src[c8 * 8];
        *(float4*)&S[6272 + c8 * 8] = *(const float4*)&src[12544 + c8 * 8];
      }
    }
#pragma unroll 1
    for (int tc = 0; tc < 5; ++tc) {
      __syncthreads();
      const int ntaps = (tc == 4) ? 1 : 2;
      // ---- stage W: linear copy from packed w3p ----
      {
        const _Float16* wsrc = w3p + icc * 27648 + tc * 6144;
        const int n8 = ntaps * 384;
        for (int c8 = tid; c8 < n8; c8 += 320) {
          *(float4*)&S[12544 + c8 * 8] = *(const float4*)&wsrc[c8 * 8];
          *(float4*)&S[18688 + c8 * 8] = *(const float4*)&wsrc[55296 + c8 * 8];
        }
      }
      __syncthreads();
#pragma unroll 1
      for (int tl = 0; tl < ntaps; ++tl) {
        const int tap = tc * 2 + tl;
        const int ky = tap / 3, kx = tap - (tap / 3) * 3;
        const int pix = (r + ky) * 14 + (c + kx);
        const int pswz = (pix >> 1) & 3;
        half8 ah[2], al[2];
#pragma unroll
        for (int s = 0; s < 2; ++s) {
          const int o = pix * 32 + ((s * 2 + g) ^ pswz) * 8;
          ah[s] = *(const half8*)&S[o];
          al[s] = *(const half8*)&S[6272 + o];
        }
#pragma unroll
        for (int nt = 0; nt < 3; ++nt) {
#pragma unroll
          for (int s = 0; s < 2; ++s) {
            const int bo = ((((tl * 3 + nt) * 2 + s) * 2 + g) * 32 + l31) * 8;
            half8 bh = *(const half8*)&S[12544 + bo];
            half8 bl = *(const half8*)&S[18688 + bo];
            acch[nt] =
                __builtin_amdgcn_mfma_f32_32x32x16_f16(ah[s], bh, acch[nt], 0, 0, 0);
            accl[nt] =
                __builtin_amdgcn_mfma_f32_32x32x16_f16(ah[s], bl, accl[nt], 0, 0, 0);
            accl[nt] =
                __builtin_amdgcn_mfma_f32_32x32x16_f16(al[s], bh, accl[nt], 0, 0, 0);
          }
        }
      }
    }
  }
  float* sO = (float*)S;
  float* outImg = feats + (size_t)img * 13824;
#pragma unroll
  for (int nt = 0; nt < 3; ++nt) {
    __syncthreads();
#pragma unroll
    for (int rr = 0; rr < 16; ++rr) {
      const int row = (rr & 3) + 8 * (rr >> 2) + 4 * g;
      const int pos = w * 32 + row;
      if (pos < 144)
        sO[l31 * 145 + pos] = acch[nt][rr] + accl[nt][rr] * 9.765625e-4f;
    }
    __syncthreads();
    for (int idx = tid; idx < 4608; idx += 320) {
      const int oc = idx / 144;
      const int pos = idx - oc * 144;
      outImg[(nt * 32 + oc) * 144 + pos] =
          fmaxf(sO[oc * 145 + pos] + b3[nt * 32 + oc], 0.f);
    }
  }
}

// ---------------------------------------------------------------------------
// ff GEMM (chunked): featsc [Cl,13824] x w_in[128,13824]^T -> P[8][2048][128]
// ---------------------------------------------------------------------------
__global__ __launch_bounds__(256) void ffgemm_k(
    const float* __restrict__ A, const float* __restrict__ Bw,
    float* __restrict__ P, int frame0, int Cl) {
  __shared__ float sA[32 * 64];
  __shared__ float sB[32 * 128];
  const int mb = blockIdx.x;
  const int kc = blockIdx.y;
  const int tid = threadIdx.x;
  const int tm = tid >> 4, tn = tid & 15;
  const int m0 = tm * 4, n0 = tn * 8;
  float acc[4][8];
#pragma unroll
  for (int m = 0; m < 4; ++m)
#pragma unroll
    for (int n = 0; n < 8; ++n) acc[m][n] = 0.f;
  const int kbase = kc * 1728;
  for (int kt = 0; kt < 1728; kt += 32) {
    __syncthreads();
#pragma unroll
    for (int i = 0; i < 2; ++i) {
      int idx = tid + i * 256;
      int row = idx >> 3, kq = idx & 7;
      int rowc = mb * 64 + row;
      if (rowc >= Cl) rowc = Cl - 1;
      float4 v = *(const float4*)(A + (size_t)rowc * 13824 + kbase + kt + kq * 4);
      sA[(kq * 4 + 0) * 64 + row] = v.x;
      sA[(kq * 4 + 1) * 64 + row] = v.y;
      sA[(kq * 4 + 2) * 64 + row] = v.z;
      sA[(kq * 4 + 3) * 64 + row] = v.w;
    }
#pragma unroll
    for (int i = 0; i < 4; ++i) {
      int idx = tid + i * 256;
      int n = idx >> 3, kq = idx & 7;
      float4 v = *(const float4*)(Bw + (size_t)n * 13824 + kbase + kt + kq * 4);
      sB[(kq * 4 + 0) * 128 + n] = v.x;
      sB[(kq * 4 + 1) * 128 + n] = v.y;
      sB[(kq * 4 + 2) * 128 + n] = v.z;
      sB[(kq * 4 + 3) * 128 + n] = v.w;
    }
    __syncthreads();
#pragma unroll
    for (int k = 0; k < 32; ++k) {
      float a4[4], b8[8];
      *(float4*)a4 = *(const float4*)&sA[k * 64 + m0];
      *(float4*)(b8) = *(const float4*)&sB[k * 128 + n0];
      *(float4*)(b8 + 4) = *(const float4*)&sB[k * 128 + n0 + 4];
#pragma unroll
      for (int m = 0; m < 4; ++m)
#pragma unroll
        for (int n = 0; n < 8; ++n) acc[m][n] += a4[m] * b8[n];
    }
  }
  float* Pp = P + ((size_t)kc * 2048 + (size_t)frame0 + (size_t)mb * 64) * 128;
#pragma unroll
  for (int m = 0; m < 4; ++m) {
    if (mb * 64 + m0 + m < Cl) {
      *(float4*)&Pp[(m0 + m) * 128 + n0] = *(float4*)&acc[m][0];
      *(float4*)&Pp[(m0 + m) * 128 + n0 + 4] = *(float4*)&acc[m][4];
    }
  }
}

__global__ __launch_bounds__(256) void ffreduce_k(const float* __restrict__ P,
                                                  float* __restrict__ ffo) {
  const int i = blockIdx.x * 256 + threadIdx.x;
  float s = 0.f;
#pragma unroll
  for (int kcc = 0; kcc < 8; ++kcc) s += P[(size_t)kcc * 262144 + i];
  ffo[i] = s;
}

// ---------------------------------------------------------------------------
// Recurrent LIF scan (unchanged)
// ---------------------------------------------------------------------------
__global__ __launch_bounds__(64) void scan_k(
    const float* __restrict__ ff, const float* __restrict__ w_rec,
    const float* __restrict__ w_fc, const float* __restrict__ b_fc,
    float* __restrict__ out) {
#pragma clang fp contract(off)
  __shared__ float sWr[16384];
  const int b = blockIdx.x;
  const int t = threadIdx.x;
  for (int idx = t; idx < 16384; idx += 64) {
    int hh = idx >> 7, j = idx & 127;
    sWr[j * 128 + hh] = w_rec[idx];
  }
  float wf0[10], wf1[10], bf[10];
#pragma unroll
  for (int c = 0; c < 10; ++c) {
    wf0[c] = w_fc[c * 128 + t];
    wf1[c] = w_fc[c * 128 + 64 + t];
    bf[c] = b_fc[c];
  }
  __syncthreads();
  float v0 = 0.f, v1 = 0.f, i0 = 0.f, i1 = 0.f;
  float vr[10], ir[10], vmax[10];
#pragma unroll
  for (int c = 0; c < 10; ++c) {
    vr[c] = 0.f;
    ir[c] = 0.f;
    vmax[c] = -1e30f;
  }
  unsigned long long pm0 = 0ull, pm1 = 0ull;
  const float* ffb = ff + (size_t)b * 8192;
#pragma unroll 1
  for (int ts = 0; ts < 64; ++ts) {
    const float vd0 = v0 + 0.1f * (i0 - v0);
    const float vd1 = v1 + 0.1f * (i1 - v1);
    const float id0 = i0 - 0.2f * i0;
    const float id1 = i1 - 0.2f * i1;
    const bool z0 = (vd0 - 0.4f) > 0.f;
    const bool z1 = (vd1 - 0.4f) > 0.f;
    v0 = z0 ? 0.f : vd0;
    v1 = z1 ? 0.f : vd1;
    float rec0 = 0.f, rec1 = 0.f;
    unsigned long long mm = pm0;
    while (mm) {
      int j = __ffsll(mm) - 1;
      mm &= mm - 1;
      rec0 += sWr[j * 128 + t];
      rec1 += sWr[j * 128 + t + 64];
    }
    mm = pm1;
    while (mm) {
      int j = __ffsll(mm) - 1;
      mm &= mm - 1;
      rec0 += sWr[(j + 64) * 128 + t];
      rec1 += sWr[(j + 64) * 128 + t + 64];
    }
    i0 = (id0 + ffb[ts * 128 + t]) + rec0;
    i1 = (id1 + ffb[ts * 128 + 64 + t]) + rec1;
    pm0 = __ballot(z0);
    pm1 = __ballot(z1);
#pragma unroll
    for (int c = 0; c < 10; ++c) {
      float val = (z0 ? wf0[c] : 0.f) + (z1 ? wf1[c] : 0.f);
      val += __shfl_xor(val, 1);
      val += __shfl_xor(val, 2);
      val += __shfl_xor(val, 4);
      val += __shfl_xor(val, 8);
      val += __shfl_xor(val, 16);
      val += __shfl_xor(val, 32);
      const float ro = val + bf[c];
      vr[c] = vr[c] + 0.1f * (ir[c] - vr[c]);
      vmax[c] = fmaxf(vmax[c], vr[c]);
      ir[c] = (ir[c] - 0.2f * ir[c]) + ro;
    }
  }
  if (t == 0) {
    float M = vmax[0];
#pragma unroll
    for (int c = 1; c < 10; ++c) M = fmaxf(M, vmax[c]);
    float s = 0.f;
#pragma unroll
    for (int c = 0; c < 10; ++c) s += expf(vmax[c] - M);
    const float ls = logf(s);
#pragma unroll
    for (int c = 0; c < 10; ++c) out[b * 10 + c] = vmax[c] - M - ls;
  }
}

// ---------------------------------------------------------------------------
extern "C" void kernel_launch(void* const* d_in, const int* in_sizes, int n_in,
                              void* d_out, int out_size, void* d_ws,
                              size_t ws_size, hipStream_t stream) {
  (void)in_sizes;
  (void)n_in;
  (void)out_size;
  const float* x = (const float*)d_in[0];
  const float* w1 = (const float*)d_in[1];
  const float* b1 = (const float*)d_in[2];
  const float* w2 = (const float*)d_in[3];
  const float* b2 = (const float*)d_in[4];
  const float* w3 = (const float*)d_in[5];
  const float* b3 = (const float*)d_in[6];
  const float* w_in = (const float*)d_in[7];
  const float* w_rec = (const float*)d_in[8];
  const float* w_fc = (const float*)d_in[9];
  const float* b_fc = (const float*)d_in[10];
  float* out = (float*)d_out;
  char* ws = (char*)d_ws;

  // ws: ff 1MB | P 8MB | w2p 144KB | w3p 216KB | per-chunk {y1h,y1l,y2s,fc}
  const size_t HDR = 1048576ull + 8388608ull + 147456ull + 221184ull;
  const size_t PERF = 115200ull + 50176ull + 55296ull;  // 220,672
  int C = 32;
  for (int c = 2048; c >= 32; c >>= 1) {
    if (HDR + (size_t)c * PERF <= ws_size) { C = c; break; }
  }
  float* ffbuf = (float*)ws;
  float* P = (float*)(ws + 1048576ull);
  _Float16* w2p = (_Float16*)(ws + 1048576ull + 8388608ull);
  _Float16* w3p = (_Float16*)(ws + 1048576ull + 8388608ull + 147456ull);
  _Float16* y1h = (_Float16*)(ws + HDR);
  _Float16* y1l = y1h + (size_t)C * 28800;
  _Float16* y2s = (_Float16*)(ws + HDR + (size_t)C * 115200ull);
  float* fc = (float*)(ws + HDR + (size_t)C * 115200ull + (size_t)C * 50176ull);

  w2prep_k<<<72, 256, 0, stream>>>(w2, w2p);
  w3prep_k<<<216, 256, 0, stream>>>(w3, w3p);

  const int nChunks = 2048 / C;
  const int mbN = (C + 63) / 64;
  for (int ch = 0; ch < nChunks; ++ch) {
    const int f0 = ch * C;
    conv1_k<<<C, 256, 0, stream>>>(x + (size_t)f0 * 4096, w1, b1, y1h, y1l);
    conv2_mfma_k<<<dim3(7, C / 2), 448, 0, stream>>>(y1h, y1l, w2p, b2, y2s);
    conv3_mfma_k<<<C, 320, 0, stream>>>(y2s, w3p, b3, fc);
    ffgemm_k<<<dim3(mbN, 8), 256, 0, stream>>>(fc, w_in, P, f0, C);
  }
  ffreduce_k<<<1024, 256, 0, stream>>>(P, ffbuf);
  scan_k<<<32, 64, 0, stream>>>(ffbuf, w_rec, w_fc, b_fc, out);
}

// Round 12
// 823.690 us; speedup vs baseline: 2.7956x; 1.2202x over previous
//
#include <hip/hip_runtime.h>
#include <math.h>

typedef _Float16 half8 __attribute__((ext_vector_type(8)));
typedef float f32x16 __attribute__((ext_vector_type(16)));

// ---------------------------------------------------------------------------
// w2prep: pack w2 [64,32,3,3] into MFMA-fragment order, split hi/lo f16.
// ---------------------------------------------------------------------------
__global__ __launch_bounds__(256) void w2prep_k(const float* __restrict__ w2,
                                                _Float16* __restrict__ w2p) {
  const int i = blockIdx.x * 256 + threadIdx.x;
  if (i >= 18432) return;
  const int tap = i >> 11;
  const int r = i & 2047;
  const int blk = r >> 8;
  const int nt = blk >> 2, s = (blk >> 1) & 1, g = blk & 1;
  const int n = (r >> 3) & 31, e = r & 7;
  const int och = nt * 32 + n;
  const int ic = s * 16 + g * 8 + e;
  const float v = w2[och * 288 + ic * 9 + tap];
  const _Float16 h = (_Float16)v;
  const _Float16 l = (_Float16)((v - (float)h) * 1024.0f);
  w2p[i] = h;
  w2p[18432 + i] = l;
}

// ---------------------------------------------------------------------------
// w3prep: pack w3 [96,64,3,3] into conv3's fragment-order image.
// ---------------------------------------------------------------------------
__global__ __launch_bounds__(256) void w3prep_k(const float* __restrict__ w3,
                                                _Float16* __restrict__ w3p) {
  const int i = blockIdx.x * 256 + threadIdx.x;
  if (i >= 55296) return;
  const int icc = i / 27648;
  const int r1 = i - icc * 27648;
  const int tc = r1 / 6144;
  const int rem = r1 - tc * 6144;
  const int tl = rem / 3072;
  const int rem2 = rem - tl * 3072;
  const int nt = rem2 >> 10;
  const int s = (rem2 >> 9) & 1;
  const int g = (rem2 >> 8) & 1;
  const int n = (rem2 >> 3) & 31;
  const int e = rem2 & 7;
  const int tap = tc * 2 + tl;
  const int och = nt * 32 + n;
  const int ic = icc * 32 + s * 16 + g * 8 + e;
  const float v = w3[(size_t)och * 576 + ic * 9 + tap];
  const _Float16 h = (_Float16)v;
  const _Float16 l = (_Float16)((v - (float)h) * 1024.0f);
  w3p[i] = h;
  w3p[55296 + i] = l;
}

// ---------------------------------------------------------------------------
// winprep: pack w_in [128,13824] into ff-GEMM B-fragment order, split f16.
// winp: hi plane [ks 864][nt 4][g 2][n 32][e 8] (1769472), then lo plane.
//   h = nt*32+n ; k = ks*16 + g*8 + e
// ---------------------------------------------------------------------------
__global__ __launch_bounds__(256) void winprep_k(const float* __restrict__ w_in,
                                                 _Float16* __restrict__ winp) {
  const int i = blockIdx.x * 256 + threadIdx.x;
  if (i >= 1769472) return;
  const int ks = i >> 11;
  const int rem = i & 2047;
  const int nt = rem >> 9;
  const int g = (rem >> 8) & 1;
  const int n = (rem >> 3) & 31;
  const int e = rem & 7;
  const int h = nt * 32 + n;
  const int k = ks * 16 + g * 8 + e;
  const float v = w_in[(size_t)h * 13824 + k];
  const _Float16 hh = (_Float16)v;
  const _Float16 ll = (_Float16)((v - (float)hh) * 1024.0f);
  winp[i] = hh;
  winp[1769472 + i] = ll;
}

// ---------------------------------------------------------------------------
// conv1: x [C,1,64,64] -> y1h/y1l [C][900 pos][32 ic^swz] f16 (split, NHWC,
// pre-swizzled). Channel-group-of-8 accumulation (no spills).
// ---------------------------------------------------------------------------
__global__ __launch_bounds__(256) void conv1_k(
    const float* __restrict__ x, const float* __restrict__ w1,
    const float* __restrict__ b1, _Float16* __restrict__ y1h,
    _Float16* __restrict__ y1l) {
  __shared__ float sIn[4096];
  __shared__ float sW[32 * 28];
  __shared__ float sB[32];
  const int img = blockIdx.x;
  const int tid = threadIdx.x;
  {
    const float4* src = (const float4*)(x + (size_t)img * 4096);
    float4* dst = (float4*)sIn;
#pragma unroll
    for (int i = 0; i < 4; ++i) dst[tid + i * 256] = src[tid + i * 256];
  }
  for (int i = tid; i < 800; i += 256) {
    int ch = i / 25, k = i % 25;
    sW[ch * 28 + k] = w1[i];
  }
  if (tid < 32) sB[tid] = b1[tid];
  __syncthreads();
  _Float16* oh = y1h + (size_t)img * 28800;
  _Float16* ol = y1l + (size_t)img * 28800;
#pragma unroll 1
  for (int it = 0; it < 2; ++it) {
    const int p0 = tid + it * 512;
    const int p1 = p0 + 256;
    const bool v1 = (p1 < 900);
    const int q1 = v1 ? p1 : 0;
    const int oy0 = p0 / 30, ox0 = p0 % 30;
    const int oy1 = q1 / 30, ox1 = q1 % 30;
    float a0[25], a1[25];
#pragma unroll
    for (int ky = 0; ky < 5; ++ky)
#pragma unroll
      for (int kx = 0; kx < 5; ++kx) {
        a0[ky * 5 + kx] = sIn[(2 * oy0 + ky) * 64 + 2 * ox0 + kx];
        a1[ky * 5 + kx] = sIn[(2 * oy1 + ky) * 64 + 2 * ox1 + kx];
      }
    const int swz0 = (ox0 >> 1) & 3;
    const int swz1 = (ox1 >> 1) & 3;
#pragma unroll 1
    for (int gb = 0; gb < 4; ++gb) {
      float acc0[8], acc1[8];
#pragma unroll
      for (int e = 0; e < 8; ++e) {
        const int ch = gb * 8 + e;
        float s0 = 0.f, s1 = 0.f;
#pragma unroll
        for (int k = 0; k < 25; ++k) {
          const float w = sW[ch * 28 + k];
          s0 += w * a0[k];
          s1 += w * a1[k];
        }
        acc0[e] = fmaxf(s0 + sB[ch], 0.f);
        acc1[e] = fmaxf(s1 + sB[ch], 0.f);
      }
      half8 h0, l0;
#pragma unroll
      for (int e = 0; e < 8; ++e) {
        const _Float16 hh = (_Float16)acc0[e];
        h0[e] = hh;
        l0[e] = (_Float16)((acc0[e] - (float)hh) * 1024.0f);
      }
      *(float4*)&oh[p0 * 32 + (gb ^ swz0) * 8] = *(float4*)&h0;
      *(float4*)&ol[p0 * 32 + (gb ^ swz0) * 8] = *(float4*)&l0;
      if (v1) {
        half8 h1, l1;
#pragma unroll
        for (int e = 0; e < 8; ++e) {
          const _Float16 hh = (_Float16)acc1[e];
          h1[e] = hh;
          l1[e] = (_Float16)((acc1[e] - (float)hh) * 1024.0f);
        }
        *(float4*)&oh[p1 * 32 + (gb ^ swz1) * 8] = *(float4*)&h1;
        *(float4*)&ol[p1 * 32 + (gb ^ swz1) * 8] = *(float4*)&l1;
      }
    }
  }
}

// ---------------------------------------------------------------------------
// conv2 + maxpool, MFMA split-f16 implicit GEMM (unchanged from R9 PASS).
// ---------------------------------------------------------------------------
__global__ __launch_bounds__(448) void conv2_mfma_k(
    const _Float16* __restrict__ y1h, const _Float16* __restrict__ y1l,
    const _Float16* __restrict__ w2p, const float* __restrict__ b2,
    _Float16* __restrict__ y2s) {
  __shared__ __align__(16) _Float16 S[31232];
  const int rp = blockIdx.x;
  const int img0 = blockIdx.y * 2;
  const int tid = threadIdx.x;
  const int row0 = rp * 4;

  {
    const _Float16* srcs[4];
    srcs[0] = y1h + (size_t)img0 * 28800 + row0 * 960;
    srcs[1] = y1h + (size_t)(img0 + 1) * 28800 + row0 * 960;
    srcs[2] = y1l + (size_t)img0 * 28800 + row0 * 960;
    srcs[3] = y1l + (size_t)(img0 + 1) * 28800 + row0 * 960;
    const int dstb[4] = {0, 5760, 11520, 17280};
#pragma unroll
    for (int seg = 0; seg < 4; ++seg) {
      const _Float16* s = srcs[seg];
      _Float16* d = &S[dstb[seg]];
      for (int c = tid; c < 720; c += 448)
        *(float4*)&d[c * 8] = *(const float4*)&s[c * 8];
    }
  }

  const int w = tid >> 6;
  const int lane = tid & 63;
  const int l31 = lane & 31;
  const int g = lane >> 5;
  const int m = w * 32 + l31;
  const int aimg = m / 112;
  const int apos = m - aimg * 112;
  const int ar = apos / 28;
  const int ax = apos - ar * 28;
  const int icg = g * 8;

  f32x16 acc00 = {}, acc01 = {}, acc10 = {}, acc11 = {};

#pragma unroll 1
  for (int tc = 0; tc < 5; ++tc) {
    __syncthreads();
    const int tap0 = tc * 2;
    const int ntaps = (tc == 4) ? 1 : 2;
    for (int c = tid; c < ntaps * 256; c += 448) {
      *(float4*)&S[23040 + c * 8] = *(const float4*)&w2p[tap0 * 2048 + c * 8];
      *(float4*)&S[27136 + c * 8] =
          *(const float4*)&w2p[18432 + tap0 * 2048 + c * 8];
    }
    __syncthreads();
#pragma unroll 1
    for (int tl = 0; tl < ntaps; ++tl) {
      const int tap = tap0 + tl;
      const int ky = tap / 3;
      const int kx = tap - ky * 3;
      const int acol = ax + kx;
      const int swzA = ((acol >> 1) & 3) << 3;
      const int abase = aimg * 5760 + ((ar + ky) * 30 + acol) * 32;
#pragma unroll
      for (int s = 0; s < 2; ++s) {
        const int icoA = (s * 16 + icg) ^ swzA;
        const int bo0 = 23040 + (((tl * 2 + 0) * 2 + s) * 2 + g) * 256 + l31 * 8;
        const int bo1 = 23040 + (((tl * 2 + 1) * 2 + s) * 2 + g) * 256 + l31 * 8;
        half8 ah = *(const half8*)&S[abase + icoA];
        half8 al = *(const half8*)&S[11520 + abase + icoA];
        half8 bh0 = *(const half8*)&S[bo0];
        half8 bl0 = *(const half8*)&S[bo0 + 4096];
        half8 bh1 = *(const half8*)&S[bo1];
        half8 bl1 = *(const half8*)&S[bo1 + 4096];
        acc00 = __builtin_amdgcn_mfma_f32_32x32x16_f16(ah, bh0, acc00, 0, 0, 0);
        acc10 = __builtin_amdgcn_mfma_f32_32x32x16_f16(ah, bl0, acc10, 0, 0, 0);
        acc10 = __builtin_amdgcn_mfma_f32_32x32x16_f16(al, bh0, acc10, 0, 0, 0);
        acc01 = __builtin_amdgcn_mfma_f32_32x32x16_f16(ah, bh1, acc01, 0, 0, 0);
        acc11 = __builtin_amdgcn_mfma_f32_32x32x16_f16(ah, bl1, acc11, 0, 0, 0);
        acc11 = __builtin_amdgcn_mfma_f32_32x32x16_f16(al, bh1, acc11, 0, 0, 0);
      }
    }
  }
  __syncthreads();
  float* sPool = (float*)S;  // [224 pos][68]
#pragma unroll
  for (int r = 0; r < 16; ++r) {
    const int mrow = (r & 3) + 8 * (r >> 2) + 4 * g;
    const int mo = w * 32 + mrow;
    sPool[mo * 68 + l31] = acc00[r] + acc10[r] * 9.765625e-4f;
    sPool[mo * 68 + 32 + l31] = acc01[r] + acc11[r] * 9.765625e-4f;
  }
  __syncthreads();
  {
    const int img = tid / 224;
    const int r1 = tid - img * 224;
    const int pr = r1 / 112;
    const int r2 = r1 - pr * 112;
    const int pc = r2 >> 3;
    const int blk = r2 & 7;
    const int m00 = img * 112 + pr * 56 + pc * 2;
    const float* s0 = &sPool[m00 * 68 + blk * 8];
    float rowv[4][8];
    *(float4*)&rowv[0][0] = *(const float4*)s0;
    *(float4*)&rowv[0][4] = *(const float4*)(s0 + 4);
    *(float4*)&rowv[1][0] = *(const float4*)(s0 + 68);
    *(float4*)&rowv[1][4] = *(const float4*)(s0 + 72);
    *(float4*)&rowv[2][0] = *(const float4*)(s0 + 28 * 68);
    *(float4*)&rowv[2][4] = *(const float4*)(s0 + 28 * 68 + 4);
    *(float4*)&rowv[3][0] = *(const float4*)(s0 + 29 * 68);
    *(float4*)&rowv[3][4] = *(const float4*)(s0 + 29 * 68 + 4);
    half8 hv, lv;
#pragma unroll
    for (int e = 0; e < 8; ++e) {
      const float mx =
          fmaxf(fmaxf(rowv[0][e], rowv[1][e]), fmaxf(rowv[2][e], rowv[3][e]));
      const float val = fmaxf(mx + b2[blk * 8 + e], 0.f);
      const _Float16 hh = (_Float16)val;
      hv[e] = hh;
      lv[e] = (_Float16)((val - (float)hh) * 1024.0f);
    }
    const int posg = (rp * 2 + pr) * 14 + pc;
    const int icc = blk >> 2;
    const int slot = (blk & 3) ^ ((posg >> 1) & 3);
    _Float16* dh =
        y2s + (size_t)(img0 + img) * 25088 + icc * 6272 + posg * 32 + slot * 8;
    *(float4*)dh = *(float4*)&hv;
    *(float4*)(dh + 12544) = *(float4*)&lv;
  }
}

// ---------------------------------------------------------------------------
// conv3 via MFMA split-f16 implicit GEMM, v3: epilogue emits SPLIT-f16
// feats planes fh/fl [img][13824] (k = och*144 + pos) for the MFMA ff-GEMM.
// ---------------------------------------------------------------------------
__global__ __launch_bounds__(320) void conv3_mfma_k(
    const _Float16* __restrict__ y2s, const _Float16* __restrict__ w3p,
    const float* __restrict__ b3, _Float16* __restrict__ fh,
    _Float16* __restrict__ fl) {
  __shared__ __align__(16) _Float16 S[24832];
  const int img = blockIdx.x;
  const int tid = threadIdx.x;
  const int w = tid >> 6;
  const int lane = tid & 63;
  const int l31 = lane & 31;
  const int g = lane >> 5;
  const int m = w * 32 + l31;
  const int mc = (m < 144) ? m : 143;
  const int r = mc / 12, c = mc - (mc / 12) * 12;

  f32x16 acch[3] = {};
  f32x16 accl[3] = {};

#pragma unroll 1
  for (int icc = 0; icc < 2; ++icc) {
    __syncthreads();
    {
      const _Float16* src = y2s + (size_t)img * 25088 + icc * 6272;
      for (int c8 = tid; c8 < 784; c8 += 320) {
        *(float4*)&S[c8 * 8] = *(const float4*)&src[c8 * 8];
        *(float4*)&S[6272 + c8 * 8] = *(const float4*)&src[12544 + c8 * 8];
      }
    }
#pragma unroll 1
    for (int tc = 0; tc < 5; ++tc) {
      __syncthreads();
      const int ntaps = (tc == 4) ? 1 : 2;
      {
        const _Float16* wsrc = w3p + icc * 27648 + tc * 6144;
        const int n8 = ntaps * 384;
        for (int c8 = tid; c8 < n8; c8 += 320) {
          *(float4*)&S[12544 + c8 * 8] = *(const float4*)&wsrc[c8 * 8];
          *(float4*)&S[18688 + c8 * 8] = *(const float4*)&wsrc[55296 + c8 * 8];
        }
      }
      __syncthreads();
#pragma unroll 1
      for (int tl = 0; tl < ntaps; ++tl) {
        const int tap = tc * 2 + tl;
        const int ky = tap / 3, kx = tap - (tap / 3) * 3;
        const int pix = (r + ky) * 14 + (c + kx);
        const int pswz = (pix >> 1) & 3;
        half8 ah[2], al[2];
#pragma unroll
        for (int s = 0; s < 2; ++s) {
          const int o = pix * 32 + ((s * 2 + g) ^ pswz) * 8;
          ah[s] = *(const half8*)&S[o];
          al[s] = *(const half8*)&S[6272 + o];
        }
#pragma unroll
        for (int nt = 0; nt < 3; ++nt) {
#pragma unroll
          for (int s = 0; s < 2; ++s) {
            const int bo = ((((tl * 3 + nt) * 2 + s) * 2 + g) * 32 + l31) * 8;
            half8 bh = *(const half8*)&S[12544 + bo];
            half8 bl = *(const half8*)&S[18688 + bo];
            acch[nt] =
                __builtin_amdgcn_mfma_f32_32x32x16_f16(ah[s], bh, acch[nt], 0, 0, 0);
            accl[nt] =
                __builtin_amdgcn_mfma_f32_32x32x16_f16(ah[s], bl, accl[nt], 0, 0, 0);
            accl[nt] =
                __builtin_amdgcn_mfma_f32_32x32x16_f16(al[s], bh, accl[nt], 0, 0, 0);
          }
        }
      }
    }
  }
  float* sO = (float*)S;
#pragma unroll
  for (int nt = 0; nt < 3; ++nt) {
    __syncthreads();
#pragma unroll
    for (int rr = 0; rr < 16; ++rr) {
      const int row = (rr & 3) + 8 * (rr >> 2) + 4 * g;
      const int pos = w * 32 + row;
      if (pos < 144)
        sO[l31 * 145 + pos] = acch[nt][rr] + accl[nt][rr] * 9.765625e-4f;
    }
    __syncthreads();
    for (int idx8 = tid; idx8 < 576; idx8 += 320) {
      const int oc = idx8 / 18;
      const int pb = idx8 - oc * 18;
      const float bb = b3[nt * 32 + oc];
      half8 hv, lv;
#pragma unroll
      for (int e = 0; e < 8; ++e) {
        const float v = fmaxf(sO[oc * 145 + pb * 8 + e] + bb, 0.f);
        const _Float16 hh = (_Float16)v;
        hv[e] = hh;
        lv[e] = (_Float16)((v - (float)hh) * 1024.0f);
      }
      const size_t ko = (size_t)img * 13824 + (nt * 32 + oc) * 144 + pb * 8;
      *(float4*)&fh[ko] = *(float4*)&hv;
      *(float4*)&fl[ko] = *(float4*)&lv;
    }
  }
}

// ---------------------------------------------------------------------------
// ff GEMM via MFMA split-f16: [Cl,13824] x w_in^T -> P[8][2048][128].
// Tile 64(M)x128(N), K_STEP=64, 256 thr (4 waves), K split 8 ways (kc).
// LDS 48KB: Ah[0,4096) [64 row][8 kb^row&7][8]; Al[4096,8192);
//           Bh[8192,16384) [ks4][nt4][g2][n32][e8]; Bl[16384,24576).
// ---------------------------------------------------------------------------
__global__ __launch_bounds__(256) void ffgemm_k(
    const _Float16* __restrict__ fh, const _Float16* __restrict__ fl,
    const _Float16* __restrict__ winp, float* __restrict__ P, int frame0,
    int Cl) {
  __shared__ __align__(16) _Float16 S[24576];
  const int mb = blockIdx.x;
  const int kc = blockIdx.y;
  const int tid = threadIdx.x;
  const int w = tid >> 6;
  const int lane = tid & 63;
  const int l31 = lane & 31;
  const int g = lane >> 5;
  const int mt = w >> 1;           // 0..1
  const int nt0 = (w & 1) * 2;     // 0 or 2
  f32x16 acc_h[2] = {};
  f32x16 acc_l[2] = {};
  const int kbase = kc * 1728;
#pragma unroll 1
  for (int kt = 0; kt < 27; ++kt) {
    __syncthreads();
    for (int i = tid; i < 512; i += 256) {
      const int row = i >> 3, kb = i & 7;
      int rc = mb * 64 + row;
      if (rc >= Cl) rc = Cl - 1;
      const size_t so = (size_t)rc * 13824 + kbase + kt * 64 + kb * 8;
      const int d = row * 64 + ((kb ^ (row & 7)) * 8);
      *(float4*)&S[d] = *(const float4*)&fh[so];
      *(float4*)&S[4096 + d] = *(const float4*)&fl[so];
    }
    {
      const size_t bo = (size_t)(kc * 108 + kt * 4) * 2048;
      for (int i = tid; i < 1024; i += 256) {
        *(float4*)&S[8192 + i * 8] = *(const float4*)&winp[bo + i * 8];
        *(float4*)&S[16384 + i * 8] =
            *(const float4*)&winp[1769472 + bo + i * 8];
      }
    }
    __syncthreads();
#pragma unroll
    for (int ks = 0; ks < 4; ++ks) {
      const int kb = ks * 2 + g;
      const int ao = (mt * 32 + l31) * 64 + ((kb ^ (l31 & 7)) * 8);
      half8 ah = *(const half8*)&S[ao];
      half8 al = *(const half8*)&S[4096 + ao];
#pragma unroll
      for (int j = 0; j < 2; ++j) {
        const int nt = nt0 + j;
        const int b = 8192 + (((ks * 4 + nt) * 2 + g) * 32 + l31) * 8;
        half8 bh = *(const half8*)&S[b];
        half8 bl = *(const half8*)&S[8192 + b];
        acc_h[j] = __builtin_amdgcn_mfma_f32_32x32x16_f16(ah, bh, acc_h[j], 0, 0, 0);
        acc_l[j] = __builtin_amdgcn_mfma_f32_32x32x16_f16(ah, bl, acc_l[j], 0, 0, 0);
        acc_l[j] = __builtin_amdgcn_mfma_f32_32x32x16_f16(al, bh, acc_l[j], 0, 0, 0);
      }
    }
  }
  float* Pp = P + ((size_t)kc * 2048 + (size_t)frame0) * 128;
#pragma unroll
  for (int j = 0; j < 2; ++j) {
    const int h = (nt0 + j) * 32 + l31;
#pragma unroll
    for (int r = 0; r < 16; ++r) {
      const int row = (r & 3) + 8 * (r >> 2) + 4 * g;
      const int fr = mb * 64 + mt * 32 + row;
      if (fr < Cl)
        Pp[(size_t)fr * 128 + h] = acc_h[j][r] + acc_l[j][r] * 9.765625e-4f;
    }
  }
}

__global__ __launch_bounds__(256) void ffreduce_k(const float* __restrict__ P,
                                                  float* __restrict__ ffo) {
  const int i = blockIdx.x * 256 + threadIdx.x;
  float s = 0.f;
#pragma unroll
  for (int kcc = 0; kcc < 8; ++kcc) s += P[(size_t)kcc * 262144 + i];
  ffo[i] = s;
}

// ---------------------------------------------------------------------------
// Recurrent LIF scan (unchanged)
// ---------------------------------------------------------------------------
__global__ __launch_bounds__(64) void scan_k(
    const float* __restrict__ ff, const float* __restrict__ w_rec,
    const float* __restrict__ w_fc, const float* __restrict__ b_fc,
    float* __restrict__ out) {
#pragma clang fp contract(off)
  __shared__ float sWr[16384];
  const int b = blockIdx.x;
  const int t = threadIdx.x;
  for (int idx = t; idx < 16384; idx += 64) {
    int hh = idx >> 7, j = idx & 127;
    sWr[j * 128 + hh] = w_rec[idx];
  }
  float wf0[10], wf1[10], bf[10];
#pragma unroll
  for (int c = 0; c < 10; ++c) {
    wf0[c] = w_fc[c * 128 + t];
    wf1[c] = w_fc[c * 128 + 64 + t];
    bf[c] = b_fc[c];
  }
  __syncthreads();
  float v0 = 0.f, v1 = 0.f, i0 = 0.f, i1 = 0.f;
  float vr[10], ir[10], vmax[10];
#pragma unroll
  for (int c = 0; c < 10; ++c) {
    vr[c] = 0.f;
    ir[c] = 0.f;
    vmax[c] = -1e30f;
  }
  unsigned long long pm0 = 0ull, pm1 = 0ull;
  const float* ffb = ff + (size_t)b * 8192;
#pragma unroll 1
  for (int ts = 0; ts < 64; ++ts) {
    const float vd0 = v0 + 0.1f * (i0 - v0);
    const float vd1 = v1 + 0.1f * (i1 - v1);
    const float id0 = i0 - 0.2f * i0;
    const float id1 = i1 - 0.2f * i1;
    const bool z0 = (vd0 - 0.4f) > 0.f;
    const bool z1 = (vd1 - 0.4f) > 0.f;
    v0 = z0 ? 0.f : vd0;
    v1 = z1 ? 0.f : vd1;
    float rec0 = 0.f, rec1 = 0.f;
    unsigned long long mm = pm0;
    while (mm) {
      int j = __ffsll(mm) - 1;
      mm &= mm - 1;
      rec0 += sWr[j * 128 + t];
      rec1 += sWr[j * 128 + t + 64];
    }
    mm = pm1;
    while (mm) {
      int j = __ffsll(mm) - 1;
      mm &= mm - 1;
      rec0 += sWr[(j + 64) * 128 + t];
      rec1 += sWr[(j + 64) * 128 + t + 64];
    }
    i0 = (id0 + ffb[ts * 128 + t]) + rec0;
    i1 = (id1 + ffb[ts * 128 + 64 + t]) + rec1;
    pm0 = __ballot(z0);
    pm1 = __ballot(z1);
#pragma unroll
    for (int c = 0; c < 10; ++c) {
      float val = (z0 ? wf0[c] : 0.f) + (z1 ? wf1[c] : 0.f);
      val += __shfl_xor(val, 1);
      val += __shfl_xor(val, 2);
      val += __shfl_xor(val, 4);
      val += __shfl_xor(val, 8);
      val += __shfl_xor(val, 16);
      val += __shfl_xor(val, 32);
      const float ro = val + bf[c];
      vr[c] = vr[c] + 0.1f * (ir[c] - vr[c]);
      vmax[c] = fmaxf(vmax[c], vr[c]);
      ir[c] = (ir[c] - 0.2f * ir[c]) + ro;
    }
  }
  if (t == 0) {
    float M = vmax[0];
#pragma unroll
    for (int c = 1; c < 10; ++c) M = fmaxf(M, vmax[c]);
    float s = 0.f;
#pragma unroll
    for (int c = 0; c < 10; ++c) s += expf(vmax[c] - M);
    const float ls = logf(s);
#pragma unroll
    for (int c = 0; c < 10; ++c) out[b * 10 + c] = vmax[c] - M - ls;
  }
}

// ---------------------------------------------------------------------------
extern "C" void kernel_launch(void* const* d_in, const int* in_sizes, int n_in,
                              void* d_out, int out_size, void* d_ws,
                              size_t ws_size, hipStream_t stream) {
  (void)in_sizes;
  (void)n_in;
  (void)out_size;
  const float* x = (const float*)d_in[0];
  const float* w1 = (const float*)d_in[1];
  const float* b1 = (const float*)d_in[2];
  const float* w2 = (const float*)d_in[3];
  const float* b2 = (const float*)d_in[4];
  const float* w3 = (const float*)d_in[5];
  const float* b3 = (const float*)d_in[6];
  const float* w_in = (const float*)d_in[7];
  const float* w_rec = (const float*)d_in[8];
  const float* w_fc = (const float*)d_in[9];
  const float* b_fc = (const float*)d_in[10];
  float* out = (float*)d_out;
  char* ws = (char*)d_ws;

  // ws: ff 1MB | P 8MB | w2p | w3p | winp (7.08MB) | per-chunk bufs
  const size_t OFF_W2P = 1048576ull + 8388608ull;              // 9,437,184
  const size_t OFF_W3P = OFF_W2P + 147456ull;                  // 9,584,640
  const size_t OFF_WIN = OFF_W3P + 221184ull;                  // 9,805,824
  const size_t HDR = OFF_WIN + 7077888ull;                     // 16,883,712
  const size_t PERF = 115200ull + 50176ull + 55296ull;         // 220,672
  int C = 32;
  for (int c = 2048; c >= 32; c >>= 1) {
    if (HDR + (size_t)c * PERF <= ws_size) { C = c; break; }
  }
  float* ffbuf = (float*)ws;
  float* P = (float*)(ws + 1048576ull);
  _Float16* w2p = (_Float16*)(ws + OFF_W2P);
  _Float16* w3p = (_Float16*)(ws + OFF_W3P);
  _Float16* winp = (_Float16*)(ws + OFF_WIN);
  _Float16* y1h = (_Float16*)(ws + HDR);
  _Float16* y1l = y1h + (size_t)C * 28800;
  _Float16* y2s = (_Float16*)(ws + HDR + (size_t)C * 115200ull);
  _Float16* fh = (_Float16*)(ws + HDR + (size_t)C * 115200ull + (size_t)C * 50176ull);
  _Float16* fl = fh + (size_t)C * 13824;

  w2prep_k<<<72, 256, 0, stream>>>(w2, w2p);
  w3prep_k<<<216, 256, 0, stream>>>(w3, w3p);
  winprep_k<<<6912, 256, 0, stream>>>(w_in, winp);

  const int nChunks = 2048 / C;
  const int mbN = (C + 63) / 64;
  for (int ch = 0; ch < nChunks; ++ch) {
    const int f0 = ch * C;
    conv1_k<<<C, 256, 0, stream>>>(x + (size_t)f0 * 4096, w1, b1, y1h, y1l);
    conv2_mfma_k<<<dim3(7, C / 2), 448, 0, stream>>>(y1h, y1l, w2p, b2, y2s);
    conv3_mfma_k<<<C, 320, 0, stream>>>(y2s, w3p, b3, fh, fl);
    ffgemm_k<<<dim3(mbN, 8), 256, 0, stream>>>(fh, fl, winp, P, f0, C);
  }
  ffreduce_k<<<1024, 256, 0, stream>>>(P, ffbuf);
  scan_k<<<32, 64, 0, stream>>>(ffbuf, w_rec, w_fc, b_fc, out);
}

// Round 13
// 807.418 us; speedup vs baseline: 2.8520x; 1.0202x over previous
//
#include <hip/hip_runtime.h>
#include <math.h>

typedef _Float16 half8 __attribute__((ext_vector_type(8)));
typedef float f32x16 __attribute__((ext_vector_type(16)));

// ---------------------------------------------------------------------------
// w2prep: pack w2 [64,32,3,3] into MFMA-fragment order, split hi/lo f16.
// ---------------------------------------------------------------------------
__global__ __launch_bounds__(256) void w2prep_k(const float* __restrict__ w2,
                                                _Float16* __restrict__ w2p) {
  const int i = blockIdx.x * 256 + threadIdx.x;
  if (i >= 18432) return;
  const int tap = i >> 11;
  const int r = i & 2047;
  const int blk = r >> 8;
  const int nt = blk >> 2, s = (blk >> 1) & 1, g = blk & 1;
  const int n = (r >> 3) & 31, e = r & 7;
  const int och = nt * 32 + n;
  const int ic = s * 16 + g * 8 + e;
  const float v = w2[och * 288 + ic * 9 + tap];
  const _Float16 h = (_Float16)v;
  const _Float16 l = (_Float16)((v - (float)h) * 1024.0f);
  w2p[i] = h;
  w2p[18432 + i] = l;
}

// ---------------------------------------------------------------------------
// w3prep: pack w3 [96,64,3,3] into conv3's fragment-order image.
// ---------------------------------------------------------------------------
__global__ __launch_bounds__(256) void w3prep_k(const float* __restrict__ w3,
                                                _Float16* __restrict__ w3p) {
  const int i = blockIdx.x * 256 + threadIdx.x;
  if (i >= 55296) return;
  const int icc = i / 27648;
  const int r1 = i - icc * 27648;
  const int tc = r1 / 6144;
  const int rem = r1 - tc * 6144;
  const int tl = rem / 3072;
  const int rem2 = rem - tl * 3072;
  const int nt = rem2 >> 10;
  const int s = (rem2 >> 9) & 1;
  const int g = (rem2 >> 8) & 1;
  const int n = (rem2 >> 3) & 31;
  const int e = rem2 & 7;
  const int tap = tc * 2 + tl;
  const int och = nt * 32 + n;
  const int ic = icc * 32 + s * 16 + g * 8 + e;
  const float v = w3[(size_t)och * 576 + ic * 9 + tap];
  const _Float16 h = (_Float16)v;
  const _Float16 l = (_Float16)((v - (float)h) * 1024.0f);
  w3p[i] = h;
  w3p[55296 + i] = l;
}

// ---------------------------------------------------------------------------
// winprep: pack w_in [128,13824] into ff-GEMM B-fragment order, split f16.
// winp: hi plane [ks 864][nt 4][g 2][n 32][e 8] (1769472), then lo plane.
// ---------------------------------------------------------------------------
__global__ __launch_bounds__(256) void winprep_k(const float* __restrict__ w_in,
                                                 _Float16* __restrict__ winp) {
  const int i = blockIdx.x * 256 + threadIdx.x;
  if (i >= 1769472) return;
  const int ks = i >> 11;
  const int rem = i & 2047;
  const int nt = rem >> 9;
  const int g = (rem >> 8) & 1;
  const int n = (rem >> 3) & 31;
  const int e = rem & 7;
  const int h = nt * 32 + n;
  const int k = ks * 16 + g * 8 + e;
  const float v = w_in[(size_t)h * 13824 + k];
  const _Float16 hh = (_Float16)v;
  const _Float16 ll = (_Float16)((v - (float)hh) * 1024.0f);
  winp[i] = hh;
  winp[1769472 + i] = ll;
}

// ---------------------------------------------------------------------------
// conv2f: FUSED conv1 + conv2 + maxpool, MFMA split-f16 implicit GEMM.
// Phase 0: stage x rows [8rp,8rp+15) (2 imgs, contiguous) + w1 + b1 into the
//          W-region overlay (f32).
// Phase 1: threads 0..359 compute conv1 (relu, 5x5 s2) for 2 imgs x 6 rows x
//          30 cols x 32ch, write split-f16 into X LDS layout (swizzled) --
//          identical producer algebra to the retired conv1_k global store.
// Phase 2+: unchanged tc-loop MFMA + pool + split-f16 NHWC store.
// LDS (hw): Xh[0,11520) Xl[11520,23040);
//   overlay in [23040,31232): xs f32 [2][960] @23040, w1 f32[800] @26880,
//   b1 f32[32] @28480; later W: Wh[23040,27136) Wl[27136,31232).
// ---------------------------------------------------------------------------
__global__ __launch_bounds__(448) void conv2f_mfma_k(
    const float* __restrict__ x, const float* __restrict__ w1,
    const float* __restrict__ b1, const _Float16* __restrict__ w2p,
    const float* __restrict__ b2, _Float16* __restrict__ y2s) {
  __shared__ __align__(16) _Float16 S[31232];
  const int rp = blockIdx.x;
  const int img0 = blockIdx.y * 2;
  const int tid = threadIdx.x;

  // ---- phase 0: stage x strips + w1 + b1 ----
  float* xs = (float*)&S[23040];   // [2][960] = 15 rows x 64
  float* w1s = (float*)&S[26880];  // [800] flat [32][25]
  float* b1s = (float*)&S[28480];  // [32]
  for (int i = tid; i < 480; i += 448) {
    const int j = i / 240, idx = i - j * 240;
    *(float4*)&xs[j * 960 + idx * 4] =
        *(const float4*)(x + (size_t)(img0 + j) * 4096 + rp * 512 + idx * 4);
  }
  for (int i = tid; i < 200; i += 448)
    *(float4*)&w1s[i * 4] = *(const float4*)(w1 + i * 4);
  if (tid < 8) *(float4*)&b1s[tid * 4] = *(const float4*)(b1 + tid * 4);
  __syncthreads();

  // ---- phase 1: conv1 for this block's 6 y1-rows, write split X to LDS ----
  if (tid < 360) {
    const int img = tid / 180;
    const int rem = tid - img * 180;
    const int row = rem / 30;
    const int col = rem - row * 30;
    float xa[25];
    const int xbase = img * 960 + (2 * row) * 64 + 2 * col;
#pragma unroll
    for (int ky = 0; ky < 5; ++ky)
#pragma unroll
      for (int kx = 0; kx < 5; ++kx) xa[ky * 5 + kx] = xs[xbase + ky * 64 + kx];
    const int swz = (col >> 1) & 3;
    const int dbase = img * 5760 + (row * 30 + col) * 32;
#pragma unroll 1
    for (int gb = 0; gb < 4; ++gb) {
      float acc[8];
#pragma unroll
      for (int e = 0; e < 8; ++e) {
        const int ch = gb * 8 + e;
        float s = 0.f;
#pragma unroll
        for (int k = 0; k < 25; ++k) s += w1s[ch * 25 + k] * xa[k];
        acc[e] = fmaxf(s + b1s[ch], 0.f);
      }
      half8 h0, l0;
#pragma unroll
      for (int e = 0; e < 8; ++e) {
        const _Float16 hh = (_Float16)acc[e];
        h0[e] = hh;
        l0[e] = (_Float16)((acc[e] - (float)hh) * 1024.0f);
      }
      const int d = dbase + (gb ^ swz) * 8;
      *(float4*)&S[d] = *(float4*)&h0;
      *(float4*)&S[11520 + d] = *(float4*)&l0;
    }
  }

  const int w = tid >> 6;
  const int lane = tid & 63;
  const int l31 = lane & 31;
  const int g = lane >> 5;
  const int m = w * 32 + l31;
  const int aimg = m / 112;
  const int apos = m - aimg * 112;
  const int ar = apos / 28;
  const int ax = apos - ar * 28;
  const int icg = g * 8;

  f32x16 acc00 = {}, acc01 = {}, acc10 = {}, acc11 = {};

#pragma unroll 1
  for (int tc = 0; tc < 5; ++tc) {
    __syncthreads();  // covers phase-1 completion before W overwrites overlay
    const int tap0 = tc * 2;
    const int ntaps = (tc == 4) ? 1 : 2;
    for (int c = tid; c < ntaps * 256; c += 448) {
      *(float4*)&S[23040 + c * 8] = *(const float4*)&w2p[tap0 * 2048 + c * 8];
      *(float4*)&S[27136 + c * 8] =
          *(const float4*)&w2p[18432 + tap0 * 2048 + c * 8];
    }
    __syncthreads();
#pragma unroll 1
    for (int tl = 0; tl < ntaps; ++tl) {
      const int tap = tap0 + tl;
      const int ky = tap / 3;
      const int kx = tap - ky * 3;
      const int acol = ax + kx;
      const int swzA = ((acol >> 1) & 3) << 3;
      const int abase = aimg * 5760 + ((ar + ky) * 30 + acol) * 32;
#pragma unroll
      for (int s = 0; s < 2; ++s) {
        const int icoA = (s * 16 + icg) ^ swzA;
        const int bo0 = 23040 + (((tl * 2 + 0) * 2 + s) * 2 + g) * 256 + l31 * 8;
        const int bo1 = 23040 + (((tl * 2 + 1) * 2 + s) * 2 + g) * 256 + l31 * 8;
        half8 ah = *(const half8*)&S[abase + icoA];
        half8 al = *(const half8*)&S[11520 + abase + icoA];
        half8 bh0 = *(const half8*)&S[bo0];
        half8 bl0 = *(const half8*)&S[bo0 + 4096];
        half8 bh1 = *(const half8*)&S[bo1];
        half8 bl1 = *(const half8*)&S[bo1 + 4096];
        acc00 = __builtin_amdgcn_mfma_f32_32x32x16_f16(ah, bh0, acc00, 0, 0, 0);
        acc10 = __builtin_amdgcn_mfma_f32_32x32x16_f16(ah, bl0, acc10, 0, 0, 0);
        acc10 = __builtin_amdgcn_mfma_f32_32x32x16_f16(al, bh0, acc10, 0, 0, 0);
        acc01 = __builtin_amdgcn_mfma_f32_32x32x16_f16(ah, bh1, acc01, 0, 0, 0);
        acc11 = __builtin_amdgcn_mfma_f32_32x32x16_f16(ah, bl1, acc11, 0, 0, 0);
        acc11 = __builtin_amdgcn_mfma_f32_32x32x16_f16(al, bh1, acc11, 0, 0, 0);
      }
    }
  }
  __syncthreads();
  float* sPool = (float*)S;  // [224 pos][68]
#pragma unroll
  for (int r = 0; r < 16; ++r) {
    const int mrow = (r & 3) + 8 * (r >> 2) + 4 * g;
    const int mo = w * 32 + mrow;
    sPool[mo * 68 + l31] = acc00[r] + acc10[r] * 9.765625e-4f;
    sPool[mo * 68 + 32 + l31] = acc01[r] + acc11[r] * 9.765625e-4f;
  }
  __syncthreads();
  {
    const int img = tid / 224;
    const int r1 = tid - img * 224;
    const int pr = r1 / 112;
    const int r2 = r1 - pr * 112;
    const int pc = r2 >> 3;
    const int blk = r2 & 7;
    const int m00 = img * 112 + pr * 56 + pc * 2;
    const float* s0 = &sPool[m00 * 68 + blk * 8];
    float rowv[4][8];
    *(float4*)&rowv[0][0] = *(const float4*)s0;
    *(float4*)&rowv[0][4] = *(const float4*)(s0 + 4);
    *(float4*)&rowv[1][0] = *(const float4*)(s0 + 68);
    *(float4*)&rowv[1][4] = *(const float4*)(s0 + 72);
    *(float4*)&rowv[2][0] = *(const float4*)(s0 + 28 * 68);
    *(float4*)&rowv[2][4] = *(const float4*)(s0 + 28 * 68 + 4);
    *(float4*)&rowv[3][0] = *(const float4*)(s0 + 29 * 68);
    *(float4*)&rowv[3][4] = *(const float4*)(s0 + 29 * 68 + 4);
    half8 hv, lv;
#pragma unroll
    for (int e = 0; e < 8; ++e) {
      const float mx =
          fmaxf(fmaxf(rowv[0][e], rowv[1][e]), fmaxf(rowv[2][e], rowv[3][e]));
      const float val = fmaxf(mx + b2[blk * 8 + e], 0.f);
      const _Float16 hh = (_Float16)val;
      hv[e] = hh;
      lv[e] = (_Float16)((val - (float)hh) * 1024.0f);
    }
    const int posg = (rp * 2 + pr) * 14 + pc;
    const int icc = blk >> 2;
    const int slot = (blk & 3) ^ ((posg >> 1) & 3);
    _Float16* dh =
        y2s + (size_t)(img0 + img) * 25088 + icc * 6272 + posg * 32 + slot * 8;
    *(float4*)dh = *(float4*)&hv;
    *(float4*)(dh + 12544) = *(float4*)&lv;
  }
}

// ---------------------------------------------------------------------------
// conv3 via MFMA split-f16 implicit GEMM (unchanged from R12 PASS).
// ---------------------------------------------------------------------------
__global__ __launch_bounds__(320) void conv3_mfma_k(
    const _Float16* __restrict__ y2s, const _Float16* __restrict__ w3p,
    const float* __restrict__ b3, _Float16* __restrict__ fh,
    _Float16* __restrict__ fl) {
  __shared__ __align__(16) _Float16 S[24832];
  const int img = blockIdx.x;
  const int tid = threadIdx.x;
  const int w = tid >> 6;
  const int lane = tid & 63;
  const int l31 = lane & 31;
  const int g = lane >> 5;
  const int m = w * 32 + l31;
  const int mc = (m < 144) ? m : 143;
  const int r = mc / 12, c = mc - (mc / 12) * 12;

  f32x16 acch[3] = {};
  f32x16 accl[3] = {};

#pragma unroll 1
  for (int icc = 0; icc < 2; ++icc) {
    __syncthreads();
    {
      const _Float16* src = y2s + (size_t)img * 25088 + icc * 6272;
      for (int c8 = tid; c8 < 784; c8 += 320) {
        *(float4*)&S[c8 * 8] = *(const float4*)&src[c8 * 8];
        *(float4*)&S[6272 + c8 * 8] = *(const float4*)&src[12544 + c8 * 8];
      }
    }
#pragma unroll 1
    for (int tc = 0; tc < 5; ++tc) {
      __syncthreads();
      const int ntaps = (tc == 4) ? 1 : 2;
      {
        const _Float16* wsrc = w3p + icc * 27648 + tc * 6144;
        const int n8 = ntaps * 384;
        for (int c8 = tid; c8 < n8; c8 += 320) {
          *(float4*)&S[12544 + c8 * 8] = *(const float4*)&wsrc[c8 * 8];
          *(float4*)&S[18688 + c8 * 8] = *(const float4*)&wsrc[55296 + c8 * 8];
        }
      }
      __syncthreads();
#pragma unroll 1
      for (int tl = 0; tl < ntaps; ++tl) {
        const int tap = tc * 2 + tl;
        const int ky = tap / 3, kx = tap - (tap / 3) * 3;
        const int pix = (r + ky) * 14 + (c + kx);
        const int pswz = (pix >> 1) & 3;
        half8 ah[2], al[2];
#pragma unroll
        for (int s = 0; s < 2; ++s) {
          const int o = pix * 32 + ((s * 2 + g) ^ pswz) * 8;
          ah[s] = *(const half8*)&S[o];
          al[s] = *(const half8*)&S[6272 + o];
        }
#pragma unroll
        for (int nt = 0; nt < 3; ++nt) {
#pragma unroll
          for (int s = 0; s < 2; ++s) {
            const int bo = ((((tl * 3 + nt) * 2 + s) * 2 + g) * 32 + l31) * 8;
            half8 bh = *(const half8*)&S[12544 + bo];
            half8 bl = *(const half8*)&S[18688 + bo];
            acch[nt] =
                __builtin_amdgcn_mfma_f32_32x32x16_f16(ah[s], bh, acch[nt], 0, 0, 0);
            accl[nt] =
                __builtin_amdgcn_mfma_f32_32x32x16_f16(ah[s], bl, accl[nt], 0, 0, 0);
            accl[nt] =
                __builtin_amdgcn_mfma_f32_32x32x16_f16(al[s], bh, accl[nt], 0, 0, 0);
          }
        }
      }
    }
  }
  float* sO = (float*)S;
#pragma unroll
  for (int nt = 0; nt < 3; ++nt) {
    __syncthreads();
#pragma unroll
    for (int rr = 0; rr < 16; ++rr) {
      const int row = (rr & 3) + 8 * (rr >> 2) + 4 * g;
      const int pos = w * 32 + row;
      if (pos < 144)
        sO[l31 * 145 + pos] = acch[nt][rr] + accl[nt][rr] * 9.765625e-4f;
    }
    __syncthreads();
    for (int idx8 = tid; idx8 < 576; idx8 += 320) {
      const int oc = idx8 / 18;
      const int pb = idx8 - oc * 18;
      const float bb = b3[nt * 32 + oc];
      half8 hv, lv;
#pragma unroll
      for (int e = 0; e < 8; ++e) {
        const float v = fmaxf(sO[oc * 145 + pb * 8 + e] + bb, 0.f);
        const _Float16 hh = (_Float16)v;
        hv[e] = hh;
        lv[e] = (_Float16)((v - (float)hh) * 1024.0f);
      }
      const size_t ko = (size_t)img * 13824 + (nt * 32 + oc) * 144 + pb * 8;
      *(float4*)&fh[ko] = *(float4*)&hv;
      *(float4*)&fl[ko] = *(float4*)&lv;
    }
  }
}

// ---------------------------------------------------------------------------
// ff GEMM via MFMA split-f16 (unchanged from R12 PASS).
// ---------------------------------------------------------------------------
__global__ __launch_bounds__(256) void ffgemm_k(
    const _Float16* __restrict__ fh, const _Float16* __restrict__ fl,
    const _Float16* __restrict__ winp, float* __restrict__ P, int frame0,
    int Cl) {
  __shared__ __align__(16) _Float16 S[24576];
  const int mb = blockIdx.x;
  const int kc = blockIdx.y;
  const int tid = threadIdx.x;
  const int w = tid >> 6;
  const int lane = tid & 63;
  const int l31 = lane & 31;
  const int g = lane >> 5;
  const int mt = w >> 1;
  const int nt0 = (w & 1) * 2;
  f32x16 acc_h[2] = {};
  f32x16 acc_l[2] = {};
  const int kbase = kc * 1728;
#pragma unroll 1
  for (int kt = 0; kt < 27; ++kt) {
    __syncthreads();
    for (int i = tid; i < 512; i += 256) {
      const int row = i >> 3, kb = i & 7;
      int rc = mb * 64 + row;
      if (rc >= Cl) rc = Cl - 1;
      const size_t so = (size_t)rc * 13824 + kbase + kt * 64 + kb * 8;
      const int d = row * 64 + ((kb ^ (row & 7)) * 8);
      *(float4*)&S[d] = *(const float4*)&fh[so];
      *(float4*)&S[4096 + d] = *(const float4*)&fl[so];
    }
    {
      const size_t bo = (size_t)(kc * 108 + kt * 4) * 2048;
      for (int i = tid; i < 1024; i += 256) {
        *(float4*)&S[8192 + i * 8] = *(const float4*)&winp[bo + i * 8];
        *(float4*)&S[16384 + i * 8] =
            *(const float4*)&winp[1769472 + bo + i * 8];
      }
    }
    __syncthreads();
#pragma unroll
    for (int ks = 0; ks < 4; ++ks) {
      const int kb = ks * 2 + g;
      const int ao = (mt * 32 + l31) * 64 + ((kb ^ (l31 & 7)) * 8);
      half8 ah = *(const half8*)&S[ao];
      half8 al = *(const half8*)&S[4096 + ao];
#pragma unroll
      for (int j = 0; j < 2; ++j) {
        const int nt = nt0 + j;
        const int b = 8192 + (((ks * 4 + nt) * 2 + g) * 32 + l31) * 8;
        half8 bh = *(const half8*)&S[b];
        half8 bl = *(const half8*)&S[8192 + b];
        acc_h[j] = __builtin_amdgcn_mfma_f32_32x32x16_f16(ah, bh, acc_h[j], 0, 0, 0);
        acc_l[j] = __builtin_amdgcn_mfma_f32_32x32x16_f16(ah, bl, acc_l[j], 0, 0, 0);
        acc_l[j] = __builtin_amdgcn_mfma_f32_32x32x16_f16(al, bh, acc_l[j], 0, 0, 0);
      }
    }
  }
  float* Pp = P + ((size_t)kc * 2048 + (size_t)frame0) * 128;
#pragma unroll
  for (int j = 0; j < 2; ++j) {
    const int h = (nt0 + j) * 32 + l31;
#pragma unroll
    for (int r = 0; r < 16; ++r) {
      const int row = (r & 3) + 8 * (r >> 2) + 4 * g;
      const int fr = mb * 64 + mt * 32 + row;
      if (fr < Cl)
        Pp[(size_t)fr * 128 + h] = acc_h[j][r] + acc_l[j][r] * 9.765625e-4f;
    }
  }
}

__global__ __launch_bounds__(256) void ffreduce_k(const float* __restrict__ P,
                                                  float* __restrict__ ffo) {
  const int i = blockIdx.x * 256 + threadIdx.x;
  float s = 0.f;
#pragma unroll
  for (int kcc = 0; kcc < 8; ++kcc) s += P[(size_t)kcc * 262144 + i];
  ffo[i] = s;
}

// ---------------------------------------------------------------------------
// Recurrent LIF scan (unchanged)
// ---------------------------------------------------------------------------
__global__ __launch_bounds__(64) void scan_k(
    const float* __restrict__ ff, const float* __restrict__ w_rec,
    const float* __restrict__ w_fc, const float* __restrict__ b_fc,
    float* __restrict__ out) {
#pragma clang fp contract(off)
  __shared__ float sWr[16384];
  const int b = blockIdx.x;
  const int t = threadIdx.x;
  for (int idx = t; idx < 16384; idx += 64) {
    int hh = idx >> 7, j = idx & 127;
    sWr[j * 128 + hh] = w_rec[idx];
  }
  float wf0[10], wf1[10], bf[10];
#pragma unroll
  for (int c = 0; c < 10; ++c) {
    wf0[c] = w_fc[c * 128 + t];
    wf1[c] = w_fc[c * 128 + 64 + t];
    bf[c] = b_fc[c];
  }
  __syncthreads();
  float v0 = 0.f, v1 = 0.f, i0 = 0.f, i1 = 0.f;
  float vr[10], ir[10], vmax[10];
#pragma unroll
  for (int c = 0; c < 10; ++c) {
    vr[c] = 0.f;
    ir[c] = 0.f;
    vmax[c] = -1e30f;
  }
  unsigned long long pm0 = 0ull, pm1 = 0ull;
  const float* ffb = ff + (size_t)b * 8192;
#pragma unroll 1
  for (int ts = 0; ts < 64; ++ts) {
    const float vd0 = v0 + 0.1f * (i0 - v0);
    const float vd1 = v1 + 0.1f * (i1 - v1);
    const float id0 = i0 - 0.2f * i0;
    const float id1 = i1 - 0.2f * i1;
    const bool z0 = (vd0 - 0.4f) > 0.f;
    const bool z1 = (vd1 - 0.4f) > 0.f;
    v0 = z0 ? 0.f : vd0;
    v1 = z1 ? 0.f : vd1;
    float rec0 = 0.f, rec1 = 0.f;
    unsigned long long mm = pm0;
    while (mm) {
      int j = __ffsll(mm) - 1;
      mm &= mm - 1;
      rec0 += sWr[j * 128 + t];
      rec1 += sWr[j * 128 + t + 64];
    }
    mm = pm1;
    while (mm) {
      int j = __ffsll(mm) - 1;
      mm &= mm - 1;
      rec0 += sWr[(j + 64) * 128 + t];
      rec1 += sWr[(j + 64) * 128 + t + 64];
    }
    i0 = (id0 + ffb[ts * 128 + t]) + rec0;
    i1 = (id1 + ffb[ts * 128 + 64 + t]) + rec1;
    pm0 = __ballot(z0);
    pm1 = __ballot(z1);
#pragma unroll
    for (int c = 0; c < 10; ++c) {
      float val = (z0 ? wf0[c] : 0.f) + (z1 ? wf1[c] : 0.f);
      val += __shfl_xor(val, 1);
      val += __shfl_xor(val, 2);
      val += __shfl_xor(val, 4);
      val += __shfl_xor(val, 8);
      val += __shfl_xor(val, 16);
      val += __shfl_xor(val, 32);
      const float ro = val + bf[c];
      vr[c] = vr[c] + 0.1f * (ir[c] - vr[c]);
      vmax[c] = fmaxf(vmax[c], vr[c]);
      ir[c] = (ir[c] - 0.2f * ir[c]) + ro;
    }
  }
  if (t == 0) {
    float M = vmax[0];
#pragma unroll
    for (int c = 1; c < 10; ++c) M = fmaxf(M, vmax[c]);
    float s = 0.f;
#pragma unroll
    for (int c = 0; c < 10; ++c) s += expf(vmax[c] - M);
    const float ls = logf(s);
#pragma unroll
    for (int c = 0; c < 10; ++c) out[b * 10 + c] = vmax[c] - M - ls;
  }
}

// ---------------------------------------------------------------------------
extern "C" void kernel_launch(void* const* d_in, const int* in_sizes, int n_in,
                              void* d_out, int out_size, void* d_ws,
                              size_t ws_size, hipStream_t stream) {
  (void)in_sizes;
  (void)n_in;
  (void)out_size;
  const float* x = (const float*)d_in[0];
  const float* w1 = (const float*)d_in[1];
  const float* b1 = (const float*)d_in[2];
  const float* w2 = (const float*)d_in[3];
  const float* b2 = (const float*)d_in[4];
  const float* w3 = (const float*)d_in[5];
  const float* b3 = (const float*)d_in[6];
  const float* w_in = (const float*)d_in[7];
  const float* w_rec = (const float*)d_in[8];
  const float* w_fc = (const float*)d_in[9];
  const float* b_fc = (const float*)d_in[10];
  float* out = (float*)d_out;
  char* ws = (char*)d_ws;

  // ws: ff 1MB | P 8MB | w2p | w3p | winp | per-chunk {y2s, fh, fl}
  const size_t OFF_W2P = 1048576ull + 8388608ull;              // 9,437,184
  const size_t OFF_W3P = OFF_W2P + 147456ull;                  // 9,584,640
  const size_t OFF_WIN = OFF_W3P + 221184ull;                  // 9,805,824
  const size_t HDR = OFF_WIN + 7077888ull;                     // 16,883,712
  const size_t PERF = 50176ull + 55296ull;                     // 105,472 (y1 gone)
  int C = 32;
  for (int c = 2048; c >= 32; c >>= 1) {
    if (HDR + (size_t)c * PERF <= ws_size) { C = c; break; }
  }
  float* ffbuf = (float*)ws;
  float* P = (float*)(ws + 1048576ull);
  _Float16* w2p = (_Float16*)(ws + OFF_W2P);
  _Float16* w3p = (_Float16*)(ws + OFF_W3P);
  _Float16* winp = (_Float16*)(ws + OFF_WIN);
  _Float16* y2s = (_Float16*)(ws + HDR);
  _Float16* fh = (_Float16*)(ws + HDR + (size_t)C * 50176ull);
  _Float16* fl = fh + (size_t)C * 13824;

  w2prep_k<<<72, 256, 0, stream>>>(w2, w2p);
  w3prep_k<<<216, 256, 0, stream>>>(w3, w3p);
  winprep_k<<<6912, 256, 0, stream>>>(w_in, winp);

  const int nChunks = 2048 / C;
  const int mbN = (C + 63) / 64;
  for (int ch = 0; ch < nChunks; ++ch) {
    const int f0 = ch * C;
    conv2f_mfma_k<<<dim3(7, C / 2), 448, 0, stream>>>(
        x + (size_t)f0 * 4096, w1, b1, w2p, b2, y2s);
    conv3_mfma_k<<<C, 320, 0, stream>>>(y2s, w3p, b3, fh, fl);
    ffgemm_k<<<dim3(mbN, 8), 256, 0, stream>>>(fh, fl, winp, P, f0, C);
  }
  ffreduce_k<<<1024, 256, 0, stream>>>(P, ffbuf);
  scan_k<<<32, 64, 0, stream>>>(ffbuf, w_rec, w_fc, b_fc, out);
}

// Round 14
// 734.770 us; speedup vs baseline: 3.1340x; 1.0989x over previous
//
#include <hip/hip_runtime.h>
#include <math.h>

typedef _Float16 half8 __attribute__((ext_vector_type(8)));
typedef float f32x16 __attribute__((ext_vector_type(16)));

// ---------------------------------------------------------------------------
// w2prep: pack w2 [64,32,3,3] into MFMA-fragment order, split hi/lo f16.
// w2p: hi [tap 9][blk 8][n 32][e 8] (18432), lo at +18432. blk=nt*4+s*2+g.
// ---------------------------------------------------------------------------
__global__ __launch_bounds__(256) void w2prep_k(const float* __restrict__ w2,
                                                _Float16* __restrict__ w2p) {
  const int i = blockIdx.x * 256 + threadIdx.x;
  if (i >= 18432) return;
  const int tap = i >> 11;
  const int r = i & 2047;
  const int blk = r >> 8;
  const int nt = blk >> 2, s = (blk >> 1) & 1, g = blk & 1;
  const int n = (r >> 3) & 31, e = r & 7;
  const int och = nt * 32 + n;
  const int ic = s * 16 + g * 8 + e;
  const float v = w2[och * 288 + ic * 9 + tap];
  const _Float16 h = (_Float16)v;
  const _Float16 l = (_Float16)((v - (float)h) * 1024.0f);
  w2p[i] = h;
  w2p[18432 + i] = l;
}

// ---------------------------------------------------------------------------
// w3prep: pack w3 [96,64,3,3] into conv3's fragment-order image.
// hi: [icc2][tc5]{tl}[nt3][s2][g2][n32][e8]; lo at +55296.
// ---------------------------------------------------------------------------
__global__ __launch_bounds__(256) void w3prep_k(const float* __restrict__ w3,
                                                _Float16* __restrict__ w3p) {
  const int i = blockIdx.x * 256 + threadIdx.x;
  if (i >= 55296) return;
  const int icc = i / 27648;
  const int r1 = i - icc * 27648;
  const int tc = r1 / 6144;
  const int rem = r1 - tc * 6144;
  const int tl = rem / 3072;
  const int rem2 = rem - tl * 3072;
  const int nt = rem2 >> 10;
  const int s = (rem2 >> 9) & 1;
  const int g = (rem2 >> 8) & 1;
  const int n = (rem2 >> 3) & 31;
  const int e = rem2 & 7;
  const int tap = tc * 2 + tl;
  const int och = nt * 32 + n;
  const int ic = icc * 32 + s * 16 + g * 8 + e;
  const float v = w3[(size_t)och * 576 + ic * 9 + tap];
  const _Float16 h = (_Float16)v;
  const _Float16 l = (_Float16)((v - (float)h) * 1024.0f);
  w3p[i] = h;
  w3p[55296 + i] = l;
}

// ---------------------------------------------------------------------------
// winprep: pack w_in [128,13824] into ff-GEMM B-fragment order, split f16.
// ---------------------------------------------------------------------------
__global__ __launch_bounds__(256) void winprep_k(const float* __restrict__ w_in,
                                                 _Float16* __restrict__ winp) {
  const int i = blockIdx.x * 256 + threadIdx.x;
  if (i >= 1769472) return;
  const int ks = i >> 11;
  const int rem = i & 2047;
  const int nt = rem >> 9;
  const int g = (rem >> 8) & 1;
  const int n = (rem >> 3) & 31;
  const int e = rem & 7;
  const int h = nt * 32 + n;
  const int k = ks * 16 + g * 8 + e;
  const float v = w_in[(size_t)h * 13824 + k];
  const _Float16 hh = (_Float16)v;
  const _Float16 ll = (_Float16)((v - (float)hh) * 1024.0f);
  winp[i] = hh;
  winp[1769472 + i] = ll;
}

// ---------------------------------------------------------------------------
// conv2f v2: FUSED conv1 + conv2 + maxpool.
// B-fragments read DIRECTLY from w2p (global, fragment-linear, L2-resident)
// -> no W LDS staging, 4 barriers total (was 12).
// LDS S[30464] hw (60928 B): Xh[0,11520) Xl[11520,23040);
//   xs f32 @hw23040 (2x960), w1s @26880 (800), b1s @28480 (32) — persistent.
//   Pool overlay (float [224][68]) reuses all of S after MFMA.
// ---------------------------------------------------------------------------
__global__ __launch_bounds__(448) void conv2f_mfma_k(
    const float* __restrict__ x, const float* __restrict__ w1,
    const float* __restrict__ b1, const _Float16* __restrict__ w2p,
    const float* __restrict__ b2, _Float16* __restrict__ y2s) {
  __shared__ __align__(16) _Float16 S[30464];
  const int rp = blockIdx.x;
  const int img0 = blockIdx.y * 2;
  const int tid = threadIdx.x;

  // ---- phase 0: stage x strips + w1 + b1 ----
  float* xs = (float*)&S[23040];   // [2][960] = 15 rows x 64
  float* w1s = (float*)&S[26880];  // [800] flat [32][25]
  float* b1s = (float*)&S[28480];  // [32]
  for (int i = tid; i < 480; i += 448) {
    const int j = i / 240, idx = i - j * 240;
    *(float4*)&xs[j * 960 + idx * 4] =
        *(const float4*)(x + (size_t)(img0 + j) * 4096 + rp * 512 + idx * 4);
  }
  for (int i = tid; i < 200; i += 448)
    *(float4*)&w1s[i * 4] = *(const float4*)(w1 + i * 4);
  if (tid < 8) *(float4*)&b1s[tid * 4] = *(const float4*)(b1 + tid * 4);
  __syncthreads();

  // ---- phase 1: conv1 for this block's 6 y1-rows, write split X to LDS ----
  if (tid < 360) {
    const int img = tid / 180;
    const int rem = tid - img * 180;
    const int row = rem / 30;
    const int col = rem - row * 30;
    float xa[25];
    const int xbase = img * 960 + (2 * row) * 64 + 2 * col;
#pragma unroll
    for (int ky = 0; ky < 5; ++ky)
#pragma unroll
      for (int kx = 0; kx < 5; ++kx) xa[ky * 5 + kx] = xs[xbase + ky * 64 + kx];
    const int swz = (col >> 1) & 3;
    const int dbase = img * 5760 + (row * 30 + col) * 32;
#pragma unroll 1
    for (int gb = 0; gb < 4; ++gb) {
      float acc[8];
#pragma unroll
      for (int e = 0; e < 8; ++e) {
        const int ch = gb * 8 + e;
        float s = 0.f;
#pragma unroll
        for (int k = 0; k < 25; ++k) s += w1s[ch * 25 + k] * xa[k];
        acc[e] = fmaxf(s + b1s[ch], 0.f);
      }
      half8 h0, l0;
#pragma unroll
      for (int e = 0; e < 8; ++e) {
        const _Float16 hh = (_Float16)acc[e];
        h0[e] = hh;
        l0[e] = (_Float16)((acc[e] - (float)hh) * 1024.0f);
      }
      const int d = dbase + (gb ^ swz) * 8;
      *(float4*)&S[d] = *(float4*)&h0;
      *(float4*)&S[11520 + d] = *(float4*)&l0;
    }
  }
  __syncthreads();

  const int w = tid >> 6;
  const int lane = tid & 63;
  const int l31 = lane & 31;
  const int g = lane >> 5;
  const int m = w * 32 + l31;
  const int aimg = m / 112;
  const int apos = m - aimg * 112;
  const int ar = apos / 28;
  const int ax = apos - ar * 28;
  const int icg = g * 8;

  f32x16 acc00 = {}, acc01 = {}, acc10 = {}, acc11 = {};

  // ---- MFMA loop: A from LDS, B direct from w2p (global) — no barriers ----
  const _Float16* bb = w2p + g * 256 + l31 * 8;
#pragma unroll 1
  for (int tap = 0; tap < 9; ++tap) {
    const int ky = tap / 3;
    const int kx = tap - ky * 3;
    const int acol = ax + kx;
    const int swzA = ((acol >> 1) & 3) << 3;
    const int abase = aimg * 5760 + ((ar + ky) * 30 + acol) * 32;
    const _Float16* bt = bb + tap * 2048;
#pragma unroll
    for (int s = 0; s < 2; ++s) {
      const int icoA = (s * 16 + icg) ^ swzA;
      half8 ah = *(const half8*)&S[abase + icoA];
      half8 al = *(const half8*)&S[11520 + abase + icoA];
      half8 bh0 = *(const half8*)&bt[s * 512];            // nt=0
      half8 bl0 = *(const half8*)&bt[18432 + s * 512];
      half8 bh1 = *(const half8*)&bt[1024 + s * 512];     // nt=1
      half8 bl1 = *(const half8*)&bt[18432 + 1024 + s * 512];
      acc00 = __builtin_amdgcn_mfma_f32_32x32x16_f16(ah, bh0, acc00, 0, 0, 0);
      acc10 = __builtin_amdgcn_mfma_f32_32x32x16_f16(ah, bl0, acc10, 0, 0, 0);
      acc10 = __builtin_amdgcn_mfma_f32_32x32x16_f16(al, bh0, acc10, 0, 0, 0);
      acc01 = __builtin_amdgcn_mfma_f32_32x32x16_f16(ah, bh1, acc01, 0, 0, 0);
      acc11 = __builtin_amdgcn_mfma_f32_32x32x16_f16(ah, bl1, acc11, 0, 0, 0);
      acc11 = __builtin_amdgcn_mfma_f32_32x32x16_f16(al, bh1, acc11, 0, 0, 0);
    }
  }
  __syncthreads();
  float* sPool = (float*)S;  // [224 pos][68]
#pragma unroll
  for (int r = 0; r < 16; ++r) {
    const int mrow = (r & 3) + 8 * (r >> 2) + 4 * g;
    const int mo = w * 32 + mrow;
    sPool[mo * 68 + l31] = acc00[r] + acc10[r] * 9.765625e-4f;
    sPool[mo * 68 + 32 + l31] = acc01[r] + acc11[r] * 9.765625e-4f;
  }
  __syncthreads();
  {
    const int img = tid / 224;
    const int r1 = tid - img * 224;
    const int pr = r1 / 112;
    const int r2 = r1 - pr * 112;
    const int pc = r2 >> 3;
    const int blk = r2 & 7;
    const int m00 = img * 112 + pr * 56 + pc * 2;
    const float* s0 = &sPool[m00 * 68 + blk * 8];
    float rowv[4][8];
    *(float4*)&rowv[0][0] = *(const float4*)s0;
    *(float4*)&rowv[0][4] = *(const float4*)(s0 + 4);
    *(float4*)&rowv[1][0] = *(const float4*)(s0 + 68);
    *(float4*)&rowv[1][4] = *(const float4*)(s0 + 72);
    *(float4*)&rowv[2][0] = *(const float4*)(s0 + 28 * 68);
    *(float4*)&rowv[2][4] = *(const float4*)(s0 + 28 * 68 + 4);
    *(float4*)&rowv[3][0] = *(const float4*)(s0 + 29 * 68);
    *(float4*)&rowv[3][4] = *(const float4*)(s0 + 29 * 68 + 4);
    half8 hv, lv;
#pragma unroll
    for (int e = 0; e < 8; ++e) {
      const float mx =
          fmaxf(fmaxf(rowv[0][e], rowv[1][e]), fmaxf(rowv[2][e], rowv[3][e]));
      const float val = fmaxf(mx + b2[blk * 8 + e], 0.f);
      const _Float16 hh = (_Float16)val;
      hv[e] = hh;
      lv[e] = (_Float16)((val - (float)hh) * 1024.0f);
    }
    const int posg = (rp * 2 + pr) * 14 + pc;
    const int icc = blk >> 2;
    const int slot = (blk & 3) ^ ((posg >> 1) & 3);
    _Float16* dh =
        y2s + (size_t)(img0 + img) * 25088 + icc * 6272 + posg * 32 + slot * 8;
    *(float4*)dh = *(float4*)&hv;
    *(float4*)(dh + 12544) = *(float4*)&lv;
  }
}

// ---------------------------------------------------------------------------
// conv3 v4: B-fragments direct from w3p (global); only X staged in LDS.
// LDS S[12544] hw (25088 B) -> up to 6 blocks/CU.
// ---------------------------------------------------------------------------
__global__ __launch_bounds__(320) void conv3_mfma_k(
    const _Float16* __restrict__ y2s, const _Float16* __restrict__ w3p,
    const float* __restrict__ b3, _Float16* __restrict__ fh,
    _Float16* __restrict__ fl) {
  __shared__ __align__(16) _Float16 S[12544];
  const int img = blockIdx.x;
  const int tid = threadIdx.x;
  const int w = tid >> 6;
  const int lane = tid & 63;
  const int l31 = lane & 31;
  const int g = lane >> 5;
  const int m = w * 32 + l31;
  const int mc = (m < 144) ? m : 143;
  const int r = mc / 12, c = mc - (mc / 12) * 12;

  f32x16 acch[3] = {};
  f32x16 accl[3] = {};

  const _Float16* bb = w3p + g * 256 + l31 * 8;
#pragma unroll 1
  for (int icc = 0; icc < 2; ++icc) {
    __syncthreads();
    {
      const _Float16* src = y2s + (size_t)img * 25088 + icc * 6272;
      for (int c8 = tid; c8 < 784; c8 += 320) {
        *(float4*)&S[c8 * 8] = *(const float4*)&src[c8 * 8];
        *(float4*)&S[6272 + c8 * 8] = *(const float4*)&src[12544 + c8 * 8];
      }
    }
    __syncthreads();
#pragma unroll 1
    for (int tc = 0; tc < 5; ++tc) {
      const int ntaps = (tc == 4) ? 1 : 2;
#pragma unroll 1
      for (int tl = 0; tl < ntaps; ++tl) {
        const int tap = tc * 2 + tl;
        const int ky = tap / 3, kx = tap - (tap / 3) * 3;
        const int pix = (r + ky) * 14 + (c + kx);
        const int pswz = (pix >> 1) & 3;
        half8 ah[2], al[2];
#pragma unroll
        for (int s = 0; s < 2; ++s) {
          const int o = pix * 32 + ((s * 2 + g) ^ pswz) * 8;
          ah[s] = *(const half8*)&S[o];
          al[s] = *(const half8*)&S[6272 + o];
        }
        const _Float16* bt = bb + icc * 27648 + tc * 6144 + tl * 3072;
#pragma unroll
        for (int nt = 0; nt < 3; ++nt) {
#pragma unroll
          for (int s = 0; s < 2; ++s) {
            const _Float16* bp = bt + nt * 1024 + s * 512;
            half8 bh = *(const half8*)bp;
            half8 bl = *(const half8*)(bp + 55296);
            acch[nt] =
                __builtin_amdgcn_mfma_f32_32x32x16_f16(ah[s], bh, acch[nt], 0, 0, 0);
            accl[nt] =
                __builtin_amdgcn_mfma_f32_32x32x16_f16(ah[s], bl, accl[nt], 0, 0, 0);
            accl[nt] =
                __builtin_amdgcn_mfma_f32_32x32x16_f16(al[s], bh, accl[nt], 0, 0, 0);
          }
        }
      }
    }
  }
  float* sO = (float*)S;  // [32][145] f32 = 18560 B <= 25088
  ;
#pragma unroll
  for (int nt = 0; nt < 3; ++nt) {
    __syncthreads();
#pragma unroll
    for (int rr = 0; rr < 16; ++rr) {
      const int row = (rr & 3) + 8 * (rr >> 2) + 4 * g;
      const int pos = w * 32 + row;
      if (pos < 144)
        sO[l31 * 145 + pos] = acch[nt][rr] + accl[nt][rr] * 9.765625e-4f;
    }
    __syncthreads();
    for (int idx8 = tid; idx8 < 576; idx8 += 320) {
      const int oc = idx8 / 18;
      const int pb = idx8 - oc * 18;
      const float bb2 = b3[nt * 32 + oc];
      half8 hv, lv;
#pragma unroll
      for (int e = 0; e < 8; ++e) {
        const float v = fmaxf(sO[oc * 145 + pb * 8 + e] + bb2, 0.f);
        const _Float16 hh = (_Float16)v;
        hv[e] = hh;
        lv[e] = (_Float16)((v - (float)hh) * 1024.0f);
      }
      const size_t ko = (size_t)img * 13824 + (nt * 32 + oc) * 144 + pb * 8;
      *(float4*)&fh[ko] = *(float4*)&hv;
      *(float4*)&fl[ko] = *(float4*)&lv;
    }
  }
}

// ---------------------------------------------------------------------------
// ff GEMM via MFMA split-f16 (unchanged from R13 PASS).
// ---------------------------------------------------------------------------
__global__ __launch_bounds__(256) void ffgemm_k(
    const _Float16* __restrict__ fh, const _Float16* __restrict__ fl,
    const _Float16* __restrict__ winp, float* __restrict__ P, int frame0,
    int Cl) {
  __shared__ __align__(16) _Float16 S[24576];
  const int mb = blockIdx.x;
  const int kc = blockIdx.y;
  const int tid = threadIdx.x;
  const int w = tid >> 6;
  const int lane = tid & 63;
  const int l31 = lane & 31;
  const int g = lane >> 5;
  const int mt = w >> 1;
  const int nt0 = (w & 1) * 2;
  f32x16 acc_h[2] = {};
  f32x16 acc_l[2] = {};
  const int kbase = kc * 1728;
#pragma unroll 1
  for (int kt = 0; kt < 27; ++kt) {
    __syncthreads();
    for (int i = tid; i < 512; i += 256) {
      const int row = i >> 3, kb = i & 7;
      int rc = mb * 64 + row;
      if (rc >= Cl) rc = Cl - 1;
      const size_t so = (size_t)rc * 13824 + kbase + kt * 64 + kb * 8;
      const int d = row * 64 + ((kb ^ (row & 7)) * 8);
      *(float4*)&S[d] = *(const float4*)&fh[so];
      *(float4*)&S[4096 + d] = *(const float4*)&fl[so];
    }
    {
      const size_t bo = (size_t)(kc * 108 + kt * 4) * 2048;
      for (int i = tid; i < 1024; i += 256) {
        *(float4*)&S[8192 + i * 8] = *(const float4*)&winp[bo + i * 8];
        *(float4*)&S[16384 + i * 8] =
            *(const float4*)&winp[1769472 + bo + i * 8];
      }
    }
    __syncthreads();
#pragma unroll
    for (int ks = 0; ks < 4; ++ks) {
      const int kb = ks * 2 + g;
      const int ao = (mt * 32 + l31) * 64 + ((kb ^ (l31 & 7)) * 8);
      half8 ah = *(const half8*)&S[ao];
      half8 al = *(const half8*)&S[4096 + ao];
#pragma unroll
      for (int j = 0; j < 2; ++j) {
        const int nt = nt0 + j;
        const int b = 8192 + (((ks * 4 + nt) * 2 + g) * 32 + l31) * 8;
        half8 bh = *(const half8*)&S[b];
        half8 bl = *(const half8*)&S[8192 + b];
        acc_h[j] = __builtin_amdgcn_mfma_f32_32x32x16_f16(ah, bh, acc_h[j], 0, 0, 0);
        acc_l[j] = __builtin_amdgcn_mfma_f32_32x32x16_f16(ah, bl, acc_l[j], 0, 0, 0);
        acc_l[j] = __builtin_amdgcn_mfma_f32_32x32x16_f16(al, bh, acc_l[j], 0, 0, 0);
      }
    }
  }
  float* Pp = P + ((size_t)kc * 2048 + (size_t)frame0) * 128;
#pragma unroll
  for (int j = 0; j < 2; ++j) {
    const int h = (nt0 + j) * 32 + l31;
#pragma unroll
    for (int r = 0; r < 16; ++r) {
      const int row = (r & 3) + 8 * (r >> 2) + 4 * g;
      const int fr = mb * 64 + mt * 32 + row;
      if (fr < Cl)
        Pp[(size_t)fr * 128 + h] = acc_h[j][r] + acc_l[j][r] * 9.765625e-4f;
    }
  }
}

__global__ __launch_bounds__(256) void ffreduce_k(const float* __restrict__ P,
                                                  float* __restrict__ ffo) {
  const int i = blockIdx.x * 256 + threadIdx.x;
  float s = 0.f;
#pragma unroll
  for (int kcc = 0; kcc < 8; ++kcc) s += P[(size_t)kcc * 262144 + i];
  ffo[i] = s;
}

// ---------------------------------------------------------------------------
// Recurrent LIF scan (unchanged)
// ---------------------------------------------------------------------------
__global__ __launch_bounds__(64) void scan_k(
    const float* __restrict__ ff, const float* __restrict__ w_rec,
    const float* __restrict__ w_fc, const float* __restrict__ b_fc,
    float* __restrict__ out) {
#pragma clang fp contract(off)
  __shared__ float sWr[16384];
  const int b = blockIdx.x;
  const int t = threadIdx.x;
  for (int idx = t; idx < 16384; idx += 64) {
    int hh = idx >> 7, j = idx & 127;
    sWr[j * 128 + hh] = w_rec[idx];
  }
  float wf0[10], wf1[10], bf[10];
#pragma unroll
  for (int c = 0; c < 10; ++c) {
    wf0[c] = w_fc[c * 128 + t];
    wf1[c] = w_fc[c * 128 + 64 + t];
    bf[c] = b_fc[c];
  }
  __syncthreads();
  float v0 = 0.f, v1 = 0.f, i0 = 0.f, i1 = 0.f;
  float vr[10], ir[10], vmax[10];
#pragma unroll
  for (int c = 0; c < 10; ++c) {
    vr[c] = 0.f;
    ir[c] = 0.f;
    vmax[c] = -1e30f;
  }
  unsigned long long pm0 = 0ull, pm1 = 0ull;
  const float* ffb = ff + (size_t)b * 8192;
#pragma unroll 1
  for (int ts = 0; ts < 64; ++ts) {
    const float vd0 = v0 + 0.1f * (i0 - v0);
    const float vd1 = v1 + 0.1f * (i1 - v1);
    const float id0 = i0 - 0.2f * i0;
    const float id1 = i1 - 0.2f * i1;
    const bool z0 = (vd0 - 0.4f) > 0.f;
    const bool z1 = (vd1 - 0.4f) > 0.f;
    v0 = z0 ? 0.f : vd0;
    v1 = z1 ? 0.f : vd1;
    float rec0 = 0.f, rec1 = 0.f;
    unsigned long long mm = pm0;
    while (mm) {
      int j = __ffsll(mm) - 1;
      mm &= mm - 1;
      rec0 += sWr[j * 128 + t];
      rec1 += sWr[j * 128 + t + 64];
    }
    mm = pm1;
    while (mm) {
      int j = __ffsll(mm) - 1;
      mm &= mm - 1;
      rec0 += sWr[(j + 64) * 128 + t];
      rec1 += sWr[(j + 64) * 128 + t + 64];
    }
    i0 = (id0 + ffb[ts * 128 + t]) + rec0;
    i1 = (id1 + ffb[ts * 128 + 64 + t]) + rec1;
    pm0 = __ballot(z0);
    pm1 = __ballot(z1);
#pragma unroll
    for (int c = 0; c < 10; ++c) {
      float val = (z0 ? wf0[c] : 0.f) + (z1 ? wf1[c] : 0.f);
      val += __shfl_xor(val, 1);
      val += __shfl_xor(val, 2);
      val += __shfl_xor(val, 4);
      val += __shfl_xor(val, 8);
      val += __shfl_xor(val, 16);
      val += __shfl_xor(val, 32);
      const float ro = val + bf[c];
      vr[c] = vr[c] + 0.1f * (ir[c] - vr[c]);
      vmax[c] = fmaxf(vmax[c], vr[c]);
      ir[c] = (ir[c] - 0.2f * ir[c]) + ro;
    }
  }
  if (t == 0) {
    float M = vmax[0];
#pragma unroll
    for (int c = 1; c < 10; ++c) M = fmaxf(M, vmax[c]);
    float s = 0.f;
#pragma unroll
    for (int c = 0; c < 10; ++c) s += expf(vmax[c] - M);
    const float ls = logf(s);
#pragma unroll
    for (int c = 0; c < 10; ++c) out[b * 10 + c] = vmax[c] - M - ls;
  }
}

// ---------------------------------------------------------------------------
extern "C" void kernel_launch(void* const* d_in, const int* in_sizes, int n_in,
                              void* d_out, int out_size, void* d_ws,
                              size_t ws_size, hipStream_t stream) {
  (void)in_sizes;
  (void)n_in;
  (void)out_size;
  const float* x = (const float*)d_in[0];
  const float* w1 = (const float*)d_in[1];
  const float* b1 = (const float*)d_in[2];
  const float* w2 = (const float*)d_in[3];
  const float* b2 = (const float*)d_in[4];
  const float* w3 = (const float*)d_in[5];
  const float* b3 = (const float*)d_in[6];
  const float* w_in = (const float*)d_in[7];
  const float* w_rec = (const float*)d_in[8];
  const float* w_fc = (const float*)d_in[9];
  const float* b_fc = (const float*)d_in[10];
  float* out = (float*)d_out;
  char* ws = (char*)d_ws;

  // ws: ff 1MB | P 8MB | w2p | w3p | winp | per-chunk {y2s, fh, fl}
  const size_t OFF_W2P = 1048576ull + 8388608ull;              // 9,437,184
  const size_t OFF_W3P = OFF_W2P + 147456ull;                  // 9,584,640
  const size_t OFF_WIN = OFF_W3P + 221184ull;                  // 9,805,824
  const size_t HDR = OFF_WIN + 7077888ull;                     // 16,883,712
  const size_t PERF = 50176ull + 55296ull;                     // 105,472
  int C = 32;
  for (int c = 2048; c >= 32; c >>= 1) {
    if (HDR + (size_t)c * PERF <= ws_size) { C = c; break; }
  }
  float* ffbuf = (float*)ws;
  float* P = (float*)(ws + 1048576ull);
  _Float16* w2p = (_Float16*)(ws + OFF_W2P);
  _Float16* w3p = (_Float16*)(ws + OFF_W3P);
  _Float16* winp = (_Float16*)(ws + OFF_WIN);
  _Float16* y2s = (_Float16*)(ws + HDR);
  _Float16* fh = (_Float16*)(ws + HDR + (size_t)C * 50176ull);
  _Float16* fl = fh + (size_t)C * 13824;

  w2prep_k<<<72, 256, 0, stream>>>(w2, w2p);
  w3prep_k<<<216, 256, 0, stream>>>(w3, w3p);
  winprep_k<<<6912, 256, 0, stream>>>(w_in, winp);

  const int nChunks = 2048 / C;
  const int mbN = (C + 63) / 64;
  for (int ch = 0; ch < nChunks; ++ch) {
    const int f0 = ch * C;
    conv2f_mfma_k<<<dim3(7, C / 2), 448, 0, stream>>>(
        x + (size_t)f0 * 4096, w1, b1, w2p, b2, y2s);
    conv3_mfma_k<<<C, 320, 0, stream>>>(y2s, w3p, b3, fh, fl);
    ffgemm_k<<<dim3(mbN, 8), 256, 0, stream>>>(fh, fl, winp, P, f0, C);
  }
  ffreduce_k<<<1024, 256, 0, stream>>>(P, ffbuf);
  scan_k<<<32, 64, 0, stream>>>(ffbuf, w_rec, w_fc, b_fc, out);
}

// Round 15
// 585.485 us; speedup vs baseline: 3.9331x; 1.2550x over previous
//
#include <hip/hip_runtime.h>
#include <math.h>

typedef _Float16 half8 __attribute__((ext_vector_type(8)));
typedef float f32x16 __attribute__((ext_vector_type(16)));

// ---------------------------------------------------------------------------
// w1prep: pack w1 [32,1,5,5] into conv1-MFMA B-fragment order, split hi/lo,
// zero-padded K 25->32. w1p: hi [blk4=s*2+g][ch 32][e 8] (1024), lo at +1024.
// ---------------------------------------------------------------------------
__global__ __launch_bounds__(256) void w1prep_k(const float* __restrict__ w1,
                                                _Float16* __restrict__ w1p) {
  const int i = blockIdx.x * 256 + threadIdx.x;
  if (i >= 1024) return;
  const int blk = i >> 8;
  const int s = blk >> 1, g = blk & 1;
  const int ch = (i >> 3) & 31, e = i & 7;
  const int k = s * 16 + g * 8 + e;
  float v = 0.f;
  if (k < 25) v = w1[ch * 25 + k];
  const _Float16 h = (_Float16)v;
  w1p[i] = h;
  w1p[1024 + i] = (_Float16)((v - (float)h) * 1024.0f);
}

// ---------------------------------------------------------------------------
// w2prep: pack w2 [64,32,3,3] into MFMA-fragment order, split hi/lo f16.
// ---------------------------------------------------------------------------
__global__ __launch_bounds__(256) void w2prep_k(const float* __restrict__ w2,
                                                _Float16* __restrict__ w2p) {
  const int i = blockIdx.x * 256 + threadIdx.x;
  if (i >= 18432) return;
  const int tap = i >> 11;
  const int r = i & 2047;
  const int blk = r >> 8;
  const int nt = blk >> 2, s = (blk >> 1) & 1, g = blk & 1;
  const int n = (r >> 3) & 31, e = r & 7;
  const int och = nt * 32 + n;
  const int ic = s * 16 + g * 8 + e;
  const float v = w2[och * 288 + ic * 9 + tap];
  const _Float16 h = (_Float16)v;
  const _Float16 l = (_Float16)((v - (float)h) * 1024.0f);
  w2p[i] = h;
  w2p[18432 + i] = l;
}

// ---------------------------------------------------------------------------
// w3prep: pack w3 [96,64,3,3] into conv3's fragment-order image.
// ---------------------------------------------------------------------------
__global__ __launch_bounds__(256) void w3prep_k(const float* __restrict__ w3,
                                                _Float16* __restrict__ w3p) {
  const int i = blockIdx.x * 256 + threadIdx.x;
  if (i >= 55296) return;
  const int icc = i / 27648;
  const int r1 = i - icc * 27648;
  const int tc = r1 / 6144;
  const int rem = r1 - tc * 6144;
  const int tl = rem / 3072;
  const int rem2 = rem - tl * 3072;
  const int nt = rem2 >> 10;
  const int s = (rem2 >> 9) & 1;
  const int g = (rem2 >> 8) & 1;
  const int n = (rem2 >> 3) & 31;
  const int e = rem2 & 7;
  const int tap = tc * 2 + tl;
  const int och = nt * 32 + n;
  const int ic = icc * 32 + s * 16 + g * 8 + e;
  const float v = w3[(size_t)och * 576 + ic * 9 + tap];
  const _Float16 h = (_Float16)v;
  const _Float16 l = (_Float16)((v - (float)h) * 1024.0f);
  w3p[i] = h;
  w3p[55296 + i] = l;
}

// ---------------------------------------------------------------------------
// winprep: pack w_in [128,13824] into ff-GEMM B-fragment order, split f16.
// ---------------------------------------------------------------------------
__global__ __launch_bounds__(256) void winprep_k(const float* __restrict__ w_in,
                                                 _Float16* __restrict__ winp) {
  const int i = blockIdx.x * 256 + threadIdx.x;
  if (i >= 1769472) return;
  const int ks = i >> 11;
  const int rem = i & 2047;
  const int nt = rem >> 9;
  const int g = (rem >> 8) & 1;
  const int n = (rem >> 3) & 31;
  const int e = rem & 7;
  const int h = nt * 32 + n;
  const int k = ks * 16 + g * 8 + e;
  const float v = w_in[(size_t)h * 13824 + k];
  const _Float16 hh = (_Float16)v;
  const _Float16 ll = (_Float16)((v - (float)hh) * 1024.0f);
  winp[i] = hh;
  winp[1769472 + i] = ll;
}

// ---------------------------------------------------------------------------
// conv2f v3: FUSED conv1(MFMA) + conv2(MFMA) + maxpool.
// Phase 0: stage x strips (f32) only.
// Phase 1: conv1 as 32x32x16 split-f16 MFMA GEMM (M=360 pos, N=32ch, K=32
//   zero-padded). A gathered per-lane from xs; B direct from w1p (global).
//   Output bias+relu+split written straight into X LDS layout.
// Phase 2: conv2 MFMA with B direct from w2p (global). Pool epilogue.
// LDS S[30464] hw: Xh[0,11520) Xl[11520,23040); xs f32 @hw23040 (2x960).
// ---------------------------------------------------------------------------
__global__ __launch_bounds__(448) void conv2f_mfma_k(
    const float* __restrict__ x, const float* __restrict__ b1,
    const _Float16* __restrict__ w1p, const _Float16* __restrict__ w2p,
    const float* __restrict__ b2, _Float16* __restrict__ y2s) {
  __shared__ __align__(16) _Float16 S[30464];
  const int rp = blockIdx.x;
  const int img0 = blockIdx.y * 2;
  const int tid = threadIdx.x;

  // ---- phase 0: stage x strips ----
  float* xs = (float*)&S[23040];  // [2][960] = 15 rows x 64
  for (int i = tid; i < 480; i += 448) {
    const int j = i / 240, idx = i - j * 240;
    *(float4*)&xs[j * 960 + idx * 4] =
        *(const float4*)(x + (size_t)(img0 + j) * 4096 + rp * 512 + idx * 4);
  }
  __syncthreads();

  const int w = tid >> 6;
  const int lane = tid & 63;
  const int l31 = lane & 31;
  const int g = lane >> 5;

  // ---- phase 1: conv1 via MFMA; 12 m-tiles of 32 positions ----
  {
    const float b1c = b1[l31];
    const int gb = l31 >> 3, e0 = l31 & 7;
#pragma unroll 1
    for (int ti = 0; ti < 2; ++ti) {
      const int t = w + ti * 7;
      if (t >= 12) break;
      const int p = t * 32 + l31;
      const int pcl = (p < 360) ? p : 359;
      const int img = pcl / 180;
      const int rem = pcl - img * 180;
      const int row = rem / 30;
      const int col = rem - row * 30;
      const int xb = img * 960 + (2 * row) * 64 + 2 * col;
      f32x16 acc_h = {}, acc_l = {};
#pragma unroll
      for (int s = 0; s < 2; ++s) {
        half8 ah, al;
#pragma unroll
        for (int e = 0; e < 8; ++e) {
          const int k = s * 16 + g * 8 + e;
          float v = 0.f;
          if (k < 25) {
            const int ky = k / 5, kx = k - (k / 5) * 5;
            v = xs[xb + ky * 64 + kx];
          }
          const _Float16 hh = (_Float16)v;
          ah[e] = hh;
          al[e] = (_Float16)((v - (float)hh) * 1024.0f);
        }
        const _Float16* bp = w1p + ((s * 2 + g) * 32 + l31) * 8;
        half8 bh = *(const half8*)bp;
        half8 bl = *(const half8*)(bp + 1024);
        acc_h = __builtin_amdgcn_mfma_f32_32x32x16_f16(ah, bh, acc_h, 0, 0, 0);
        acc_l = __builtin_amdgcn_mfma_f32_32x32x16_f16(ah, bl, acc_l, 0, 0, 0);
        acc_l = __builtin_amdgcn_mfma_f32_32x32x16_f16(al, bh, acc_l, 0, 0, 0);
      }
#pragma unroll
      for (int r = 0; r < 16; ++r) {
        const int mrow = (r & 3) + 8 * (r >> 2) + 4 * g;
        const int pp = t * 32 + mrow;
        if (pp < 360) {
          const int im = pp / 180;
          const int rm = pp - im * 180;
          const int cl = rm - (rm / 30) * 30;
          const int swz = (cl >> 1) & 3;
          const int addr = im * 5760 + rm * 32 + ((gb ^ swz) << 3) + e0;
          const float val =
              fmaxf(acc_h[r] + acc_l[r] * 9.765625e-4f + b1c, 0.f);
          const _Float16 hh = (_Float16)val;
          S[addr] = hh;
          S[11520 + addr] = (_Float16)((val - (float)hh) * 1024.0f);
        }
      }
    }
  }
  __syncthreads();

  const int m = w * 32 + l31;
  const int aimg = m / 112;
  const int apos = m - aimg * 112;
  const int ar = apos / 28;
  const int ax = apos - ar * 28;
  const int icg = g * 8;

  f32x16 acc00 = {}, acc01 = {}, acc10 = {}, acc11 = {};

  // ---- phase 2: conv2 MFMA; A from LDS, B direct from w2p ----
  const _Float16* bb = w2p + g * 256 + l31 * 8;
#pragma unroll 1
  for (int tap = 0; tap < 9; ++tap) {
    const int ky = tap / 3;
    const int kx = tap - ky * 3;
    const int acol = ax + kx;
    const int swzA = ((acol >> 1) & 3) << 3;
    const int abase = aimg * 5760 + ((ar + ky) * 30 + acol) * 32;
    const _Float16* bt = bb + tap * 2048;
#pragma unroll
    for (int s = 0; s < 2; ++s) {
      const int icoA = (s * 16 + icg) ^ swzA;
      half8 ah = *(const half8*)&S[abase + icoA];
      half8 al = *(const half8*)&S[11520 + abase + icoA];
      half8 bh0 = *(const half8*)&bt[s * 512];
      half8 bl0 = *(const half8*)&bt[18432 + s * 512];
      half8 bh1 = *(const half8*)&bt[1024 + s * 512];
      half8 bl1 = *(const half8*)&bt[18432 + 1024 + s * 512];
      acc00 = __builtin_amdgcn_mfma_f32_32x32x16_f16(ah, bh0, acc00, 0, 0, 0);
      acc10 = __builtin_amdgcn_mfma_f32_32x32x16_f16(ah, bl0, acc10, 0, 0, 0);
      acc10 = __builtin_amdgcn_mfma_f32_32x32x16_f16(al, bh0, acc10, 0, 0, 0);
      acc01 = __builtin_amdgcn_mfma_f32_32x32x16_f16(ah, bh1, acc01, 0, 0, 0);
      acc11 = __builtin_amdgcn_mfma_f32_32x32x16_f16(ah, bl1, acc11, 0, 0, 0);
      acc11 = __builtin_amdgcn_mfma_f32_32x32x16_f16(al, bh1, acc11, 0, 0, 0);
    }
  }
  __syncthreads();
  float* sPool = (float*)S;  // [224 pos][68]
#pragma unroll
  for (int r = 0; r < 16; ++r) {
    const int mrow = (r & 3) + 8 * (r >> 2) + 4 * g;
    const int mo = w * 32 + mrow;
    sPool[mo * 68 + l31] = acc00[r] + acc10[r] * 9.765625e-4f;
    sPool[mo * 68 + 32 + l31] = acc01[r] + acc11[r] * 9.765625e-4f;
  }
  __syncthreads();
  {
    const int img = tid / 224;
    const int r1 = tid - img * 224;
    const int pr = r1 / 112;
    const int r2 = r1 - pr * 112;
    const int pc = r2 >> 3;
    const int blk = r2 & 7;
    const int m00 = img * 112 + pr * 56 + pc * 2;
    const float* s0 = &sPool[m00 * 68 + blk * 8];
    float rowv[4][8];
    *(float4*)&rowv[0][0] = *(const float4*)s0;
    *(float4*)&rowv[0][4] = *(const float4*)(s0 + 4);
    *(float4*)&rowv[1][0] = *(const float4*)(s0 + 68);
    *(float4*)&rowv[1][4] = *(const float4*)(s0 + 72);
    *(float4*)&rowv[2][0] = *(const float4*)(s0 + 28 * 68);
    *(float4*)&rowv[2][4] = *(const float4*)(s0 + 28 * 68 + 4);
    *(float4*)&rowv[3][0] = *(const float4*)(s0 + 29 * 68);
    *(float4*)&rowv[3][4] = *(const float4*)(s0 + 29 * 68 + 4);
    half8 hv, lv;
#pragma unroll
    for (int e = 0; e < 8; ++e) {
      const float mx =
          fmaxf(fmaxf(rowv[0][e], rowv[1][e]), fmaxf(rowv[2][e], rowv[3][e]));
      const float val = fmaxf(mx + b2[blk * 8 + e], 0.f);
      const _Float16 hh = (_Float16)val;
      hv[e] = hh;
      lv[e] = (_Float16)((val - (float)hh) * 1024.0f);
    }
    const int posg = (rp * 2 + pr) * 14 + pc;
    const int icc = blk >> 2;
    const int slot = (blk & 3) ^ ((posg >> 1) & 3);
    _Float16* dh =
        y2s + (size_t)(img0 + img) * 25088 + icc * 6272 + posg * 32 + slot * 8;
    *(float4*)dh = *(float4*)&hv;
    *(float4*)(dh + 12544) = *(float4*)&lv;
  }
}

// ---------------------------------------------------------------------------
// conv3 v4: B-fragments direct from w3p (global); only X staged in LDS.
// ---------------------------------------------------------------------------
__global__ __launch_bounds__(320) void conv3_mfma_k(
    const _Float16* __restrict__ y2s, const _Float16* __restrict__ w3p,
    const float* __restrict__ b3, _Float16* __restrict__ fh,
    _Float16* __restrict__ fl) {
  __shared__ __align__(16) _Float16 S[12544];
  const int img = blockIdx.x;
  const int tid = threadIdx.x;
  const int w = tid >> 6;
  const int lane = tid & 63;
  const int l31 = lane & 31;
  const int g = lane >> 5;
  const int m = w * 32 + l31;
  const int mc = (m < 144) ? m : 143;
  const int r = mc / 12, c = mc - (mc / 12) * 12;

  f32x16 acch[3] = {};
  f32x16 accl[3] = {};

  const _Float16* bb = w3p + g * 256 + l31 * 8;
#pragma unroll 1
  for (int icc = 0; icc < 2; ++icc) {
    __syncthreads();
    {
      const _Float16* src = y2s + (size_t)img * 25088 + icc * 6272;
      for (int c8 = tid; c8 < 784; c8 += 320) {
        *(float4*)&S[c8 * 8] = *(const float4*)&src[c8 * 8];
        *(float4*)&S[6272 + c8 * 8] = *(const float4*)&src[12544 + c8 * 8];
      }
    }
    __syncthreads();
#pragma unroll 1
    for (int tc = 0; tc < 5; ++tc) {
      const int ntaps = (tc == 4) ? 1 : 2;
#pragma unroll 1
      for (int tl = 0; tl < ntaps; ++tl) {
        const int tap = tc * 2 + tl;
        const int ky = tap / 3, kx = tap - (tap / 3) * 3;
        const int pix = (r + ky) * 14 + (c + kx);
        const int pswz = (pix >> 1) & 3;
        half8 ah[2], al[2];
#pragma unroll
        for (int s = 0; s < 2; ++s) {
          const int o = pix * 32 + ((s * 2 + g) ^ pswz) * 8;
          ah[s] = *(const half8*)&S[o];
          al[s] = *(const half8*)&S[6272 + o];
        }
        const _Float16* bt = bb + icc * 27648 + tc * 6144 + tl * 3072;
#pragma unroll
        for (int nt = 0; nt < 3; ++nt) {
#pragma unroll
          for (int s = 0; s < 2; ++s) {
            const _Float16* bp = bt + nt * 1024 + s * 512;
            half8 bh = *(const half8*)bp;
            half8 bl = *(const half8*)(bp + 55296);
            acch[nt] =
                __builtin_amdgcn_mfma_f32_32x32x16_f16(ah[s], bh, acch[nt], 0, 0, 0);
            accl[nt] =
                __builtin_amdgcn_mfma_f32_32x32x16_f16(ah[s], bl, accl[nt], 0, 0, 0);
            accl[nt] =
                __builtin_amdgcn_mfma_f32_32x32x16_f16(al[s], bh, accl[nt], 0, 0, 0);
          }
        }
      }
    }
  }
  float* sO = (float*)S;
#pragma unroll
  for (int nt = 0; nt < 3; ++nt) {
    __syncthreads();
#pragma unroll
    for (int rr = 0; rr < 16; ++rr) {
      const int row = (rr & 3) + 8 * (rr >> 2) + 4 * g;
      const int pos = w * 32 + row;
      if (pos < 144)
        sO[l31 * 145 + pos] = acch[nt][rr] + accl[nt][rr] * 9.765625e-4f;
    }
    __syncthreads();
    for (int idx8 = tid; idx8 < 576; idx8 += 320) {
      const int oc = idx8 / 18;
      const int pb = idx8 - oc * 18;
      const float bb2 = b3[nt * 32 + oc];
      half8 hv, lv;
#pragma unroll
      for (int e = 0; e < 8; ++e) {
        const float v = fmaxf(sO[oc * 145 + pb * 8 + e] + bb2, 0.f);
        const _Float16 hh = (_Float16)v;
        hv[e] = hh;
        lv[e] = (_Float16)((v - (float)hh) * 1024.0f);
      }
      const size_t ko = (size_t)img * 13824 + (nt * 32 + oc) * 144 + pb * 8;
      *(float4*)&fh[ko] = *(float4*)&hv;
      *(float4*)&fl[ko] = *(float4*)&lv;
    }
  }
}

// ---------------------------------------------------------------------------
// ff GEMM via MFMA split-f16 (unchanged).
// ---------------------------------------------------------------------------
__global__ __launch_bounds__(256) void ffgemm_k(
    const _Float16* __restrict__ fh, const _Float16* __restrict__ fl,
    const _Float16* __restrict__ winp, float* __restrict__ P, int frame0,
    int Cl) {
  __shared__ __align__(16) _Float16 S[24576];
  const int mb = blockIdx.x;
  const int kc = blockIdx.y;
  const int tid = threadIdx.x;
  const int w = tid >> 6;
  const int lane = tid & 63;
  const int l31 = lane & 31;
  const int g = lane >> 5;
  const int mt = w >> 1;
  const int nt0 = (w & 1) * 2;
  f32x16 acc_h[2] = {};
  f32x16 acc_l[2] = {};
  const int kbase = kc * 1728;
#pragma unroll 1
  for (int kt = 0; kt < 27; ++kt) {
    __syncthreads();
    for (int i = tid; i < 512; i += 256) {
      const int row = i >> 3, kb = i & 7;
      int rc = mb * 64 + row;
      if (rc >= Cl) rc = Cl - 1;
      const size_t so = (size_t)rc * 13824 + kbase + kt * 64 + kb * 8;
      const int d = row * 64 + ((kb ^ (row & 7)) * 8);
      *(float4*)&S[d] = *(const float4*)&fh[so];
      *(float4*)&S[4096 + d] = *(const float4*)&fl[so];
    }
    {
      const size_t bo = (size_t)(kc * 108 + kt * 4) * 2048;
      for (int i = tid; i < 1024; i += 256) {
        *(float4*)&S[8192 + i * 8] = *(const float4*)&winp[bo + i * 8];
        *(float4*)&S[16384 + i * 8] =
            *(const float4*)&winp[1769472 + bo + i * 8];
      }
    }
    __syncthreads();
#pragma unroll
    for (int ks = 0; ks < 4; ++ks) {
      const int kb = ks * 2 + g;
      const int ao = (mt * 32 + l31) * 64 + ((kb ^ (l31 & 7)) * 8);
      half8 ah = *(const half8*)&S[ao];
      half8 al = *(const half8*)&S[4096 + ao];
#pragma unroll
      for (int j = 0; j < 2; ++j) {
        const int nt = nt0 + j;
        const int b = 8192 + (((ks * 4 + nt) * 2 + g) * 32 + l31) * 8;
        half8 bh = *(const half8*)&S[b];
        half8 bl = *(const half8*)&S[8192 + b];
        acc_h[j] = __builtin_amdgcn_mfma_f32_32x32x16_f16(ah, bh, acc_h[j], 0, 0, 0);
        acc_l[j] = __builtin_amdgcn_mfma_f32_32x32x16_f16(ah, bl, acc_l[j], 0, 0, 0);
        acc_l[j] = __builtin_amdgcn_mfma_f32_32x32x16_f16(al, bh, acc_l[j], 0, 0, 0);
      }
    }
  }
  float* Pp = P + ((size_t)kc * 2048 + (size_t)frame0) * 128;
#pragma unroll
  for (int j = 0; j < 2; ++j) {
    const int h = (nt0 + j) * 32 + l31;
#pragma unroll
    for (int r = 0; r < 16; ++r) {
      const int row = (r & 3) + 8 * (r >> 2) + 4 * g;
      const int fr = mb * 64 + mt * 32 + row;
      if (fr < Cl)
        Pp[(size_t)fr * 128 + h] = acc_h[j][r] + acc_l[j][r] * 9.765625e-4f;
    }
  }
}

__global__ __launch_bounds__(256) void ffreduce_k(const float* __restrict__ P,
                                                  float* __restrict__ ffo) {
  const int i = blockIdx.x * 256 + threadIdx.x;
  float s = 0.f;
#pragma unroll
  for (int kcc = 0; kcc < 8; ++kcc) s += P[(size_t)kcc * 262144 + i];
  ffo[i] = s;
}

// ---------------------------------------------------------------------------
// Recurrent LIF scan (unchanged)
// ---------------------------------------------------------------------------
__global__ __launch_bounds__(64) void scan_k(
    const float* __restrict__ ff, const float* __restrict__ w_rec,
    const float* __restrict__ w_fc, const float* __restrict__ b_fc,
    float* __restrict__ out) {
#pragma clang fp contract(off)
  __shared__ float sWr[16384];
  const int b = blockIdx.x;
  const int t = threadIdx.x;
  for (int idx = t; idx < 16384; idx += 64) {
    int hh = idx >> 7, j = idx & 127;
    sWr[j * 128 + hh] = w_rec[idx];
  }
  float wf0[10], wf1[10], bf[10];
#pragma unroll
  for (int c = 0; c < 10; ++c) {
    wf0[c] = w_fc[c * 128 + t];
    wf1[c] = w_fc[c * 128 + 64 + t];
    bf[c] = b_fc[c];
  }
  __syncthreads();
  float v0 = 0.f, v1 = 0.f, i0 = 0.f, i1 = 0.f;
  float vr[10], ir[10], vmax[10];
#pragma unroll
  for (int c = 0; c < 10; ++c) {
    vr[c] = 0.f;
    ir[c] = 0.f;
    vmax[c] = -1e30f;
  }
  unsigned long long pm0 = 0ull, pm1 = 0ull;
  const float* ffb = ff + (size_t)b * 8192;
#pragma unroll 1
  for (int ts = 0; ts < 64; ++ts) {
    const float vd0 = v0 + 0.1f * (i0 - v0);
    const float vd1 = v1 + 0.1f * (i1 - v1);
    const float id0 = i0 - 0.2f * i0;
    const float id1 = i1 - 0.2f * i1;
    const bool z0 = (vd0 - 0.4f) > 0.f;
    const bool z1 = (vd1 - 0.4f) > 0.f;
    v0 = z0 ? 0.f : vd0;
    v1 = z1 ? 0.f : vd1;
    float rec0 = 0.f, rec1 = 0.f;
    unsigned long long mm = pm0;
    while (mm) {
      int j = __ffsll(mm) - 1;
      mm &= mm - 1;
      rec0 += sWr[j * 128 + t];
      rec1 += sWr[j * 128 + t + 64];
    }
    mm = pm1;
    while (mm) {
      int j = __ffsll(mm) - 1;
      mm &= mm - 1;
      rec0 += sWr[(j + 64) * 128 + t];
      rec1 += sWr[(j + 64) * 128 + t + 64];
    }
    i0 = (id0 + ffb[ts * 128 + t]) + rec0;
    i1 = (id1 + ffb[ts * 128 + 64 + t]) + rec1;
    pm0 = __ballot(z0);
    pm1 = __ballot(z1);
#pragma unroll
    for (int c = 0; c < 10; ++c) {
      float val = (z0 ? wf0[c] : 0.f) + (z1 ? wf1[c] : 0.f);
      val += __shfl_xor(val, 1);
      val += __shfl_xor(val, 2);
      val += __shfl_xor(val, 4);
      val += __shfl_xor(val, 8);
      val += __shfl_xor(val, 16);
      val += __shfl_xor(val, 32);
      const float ro = val + bf[c];
      vr[c] = vr[c] + 0.1f * (ir[c] - vr[c]);
      vmax[c] = fmaxf(vmax[c], vr[c]);
      ir[c] = (ir[c] - 0.2f * ir[c]) + ro;
    }
  }
  if (t == 0) {
    float M = vmax[0];
#pragma unroll
    for (int c = 1; c < 10; ++c) M = fmaxf(M, vmax[c]);
    float s = 0.f;
#pragma unroll
    for (int c = 0; c < 10; ++c) s += expf(vmax[c] - M);
    const float ls = logf(s);
#pragma unroll
    for (int c = 0; c < 10; ++c) out[b * 10 + c] = vmax[c] - M - ls;
  }
}

// ---------------------------------------------------------------------------
extern "C" void kernel_launch(void* const* d_in, const int* in_sizes, int n_in,
                              void* d_out, int out_size, void* d_ws,
                              size_t ws_size, hipStream_t stream) {
  (void)in_sizes;
  (void)n_in;
  (void)out_size;
  const float* x = (const float*)d_in[0];
  const float* w1 = (const float*)d_in[1];
  const float* b1 = (const float*)d_in[2];
  const float* w2 = (const float*)d_in[3];
  const float* b2 = (const float*)d_in[4];
  const float* w3 = (const float*)d_in[5];
  const float* b3 = (const float*)d_in[6];
  const float* w_in = (const float*)d_in[7];
  const float* w_rec = (const float*)d_in[8];
  const float* w_fc = (const float*)d_in[9];
  const float* b_fc = (const float*)d_in[10];
  float* out = (float*)d_out;
  char* ws = (char*)d_ws;

  // ws: ff 1MB | P 8MB | w2p | w3p | winp | w1p | per-chunk {y2s, fh, fl}
  const size_t OFF_W2P = 1048576ull + 8388608ull;              // 9,437,184
  const size_t OFF_W3P = OFF_W2P + 147456ull;                  // 9,584,640
  const size_t OFF_WIN = OFF_W3P + 221184ull;                  // 9,805,824
  const size_t OFF_W1P = OFF_WIN + 7077888ull;                 // 16,883,712
  const size_t HDR = OFF_W1P + 8192ull;                        // 16,891,904
  const size_t PERF = 50176ull + 55296ull;                     // 105,472
  int C = 32;
  for (int c = 2048; c >= 32; c >>= 1) {
    if (HDR + (size_t)c * PERF <= ws_size) { C = c; break; }
  }
  float* ffbuf = (float*)ws;
  float* P = (float*)(ws + 1048576ull);
  _Float16* w2p = (_Float16*)(ws + OFF_W2P);
  _Float16* w3p = (_Float16*)(ws + OFF_W3P);
  _Float16* winp = (_Float16*)(ws + OFF_WIN);
  _Float16* w1p = (_Float16*)(ws + OFF_W1P);
  _Float16* y2s = (_Float16*)(ws + HDR);
  _Float16* fh = (_Float16*)(ws + HDR + (size_t)C * 50176ull);
  _Float16* fl = fh + (size_t)C * 13824;

  w1prep_k<<<4, 256, 0, stream>>>(w1, w1p);
  w2prep_k<<<72, 256, 0, stream>>>(w2, w2p);
  w3prep_k<<<216, 256, 0, stream>>>(w3, w3p);
  winprep_k<<<6912, 256, 0, stream>>>(w_in, winp);

  const int nChunks = 2048 / C;
  const int mbN = (C + 63) / 64;
  for (int ch = 0; ch < nChunks; ++ch) {
    const int f0 = ch * C;
    conv2f_mfma_k<<<dim3(7, C / 2), 448, 0, stream>>>(
        x + (size_t)f0 * 4096, b1, w1p, w2p, b2, y2s);
    conv3_mfma_k<<<C, 320, 0, stream>>>(y2s, w3p, b3, fh, fl);
    ffgemm_k<<<dim3(mbN, 8), 256, 0, stream>>>(fh, fl, winp, P, f0, C);
  }
  ffreduce_k<<<1024, 256, 0, stream>>>(P, ffbuf);
  scan_k<<<32, 64, 0, stream>>>(ffbuf, w_rec, w_fc, b_fc, out);
}